// Round 11
// baseline (324.602 us; speedup 1.0000x reference)
//
#include <hip/hip_runtime.h>

typedef unsigned short u16;
typedef unsigned int   u32;
typedef unsigned char  u8;
typedef unsigned long long u64;

#define B_TOT 512
#define L_SEQ 256
#define D_IN  64
#define HIDN  256
#define TOPK  128
#define CAP   160              // candidate cap per unit (both paths)
#define NWT   32               // units per batch (both paths)
#define FLDS  113280           // fused dynamic LDS bytes

typedef float  f32x4  __attribute__((ext_vector_type(4)));
typedef __bf16 bf16x8 __attribute__((ext_vector_type(8)));

// ---------- helpers ----------
__device__ __forceinline__ u16 f2bf(float f){
  u32 u = __float_as_uint(f);
  u32 r = u + 0x7fffu + ((u>>16)&1u);   // RNE
  return (u16)(r>>16);
}
__device__ __forceinline__ u32 sortKey(float f){
  u32 b = __float_as_uint(f);
  return (b & 0x80000000u) ? ~b : (b | 0x80000000u);
}
__device__ __forceinline__ float unKey(u32 u){
  u32 b = (u & 0x80000000u) ? (u & 0x7fffffffu) : ~u;
  return __uint_as_float(b);
}
__device__ __forceinline__ void cvt8(const float* v, u32* hp, u32* lp){
  #pragma unroll
  for (int i=0;i<4;++i){
    float v0 = v[2*i], v1 = v[2*i+1];
    u16 h0 = f2bf(v0); float h0f = __uint_as_float(((u32)h0)<<16); u16 l0 = f2bf(v0 - h0f);
    u16 h1 = f2bf(v1); float h1f = __uint_as_float(((u32)h1)<<16); u16 l1 = f2bf(v1 - h1f);
    hp[i] = (u32)h0 | ((u32)h1<<16);
    lp[i] = (u32)l0 | ((u32)l1<<16);
  }
}

// ---------- K0: fused weight prep ----------
__global__ __launch_bounds__(256) void k_wprep(
    const float* __restrict__ Wq, const float* __restrict__ bq,
    const float* __restrict__ Wk, const float* __restrict__ bk,
    const float* __restrict__ xi_w1, const float* __restrict__ phi_w1,
    u16* __restrict__ MtH, u16* __restrict__ MtL, float* __restrict__ uvc,
    u16* __restrict__ xiH, u16* __restrict__ xiL,
    u16* __restrict__ phiH, u16* __restrict__ phiL)
{
  int bid = blockIdx.x, tid = threadIdx.x;
  if (bid < 64){
    __shared__ float wq[HIDN];
    __shared__ float part[256];
    int a = bid;
    wq[tid] = Wq[a*HIDN + tid];
    __syncthreads();
    int bcol = tid & 63, q = tid >> 6;
    float s = 0.f;
    for (int h = q*64; h < q*64 + 64; ++h)
      s = fmaf(wq[h], Wk[bcol*HIDN + h], s);
    part[tid] = s;
    __syncthreads();
    if (tid < 64){
      float mv = part[tid] + part[64+tid] + part[128+tid] + part[192+tid];
      u16 hh = f2bf(mv); float hf = __uint_as_float(((u32)hh)<<16);
      u16 ll = f2bf(mv - hf);
      MtH[tid*64 + a] = hh;          // Mt[c][a] = M[a][c]
      MtL[tid*64 + a] = ll;
    }
    if (tid == 0){
      float su = 0.f;
      for (int h=0; h<HIDN; ++h) su = fmaf(wq[h], bk[h], su);
      uvc[a] = su;
    }
    if (tid == 1){
      float sv = 0.f;
      for (int h=0; h<HIDN; ++h) sv = fmaf(Wk[a*HIDN + h], bq[h], sv);
      uvc[64 + a] = sv;
    }
    if (a == 0 && tid == 2){
      float c = 0.f;
      for (int h=0; h<HIDN; ++h) c = fmaf(bq[h], bk[h], c);
      uvc[128] = c;
    }
  } else {
    int t = (bid-64)*256 + tid;
    if (t < 256*128){
      int h = t >> 7, d = t & 127;
      float v = xi_w1[d*HIDN + h];
      u16 hh = f2bf(v); float hf = __uint_as_float(((u32)hh)<<16);
      u16 ll = f2bf(v - hf);
      xiH[h*128 + d] = hh; xiL[h*128 + d] = ll;
    } else {
      int t2 = t - 256*128;
      int h = t2 >> 6, d = t2 & 63;
      float v = phi_w1[d*HIDN + h];
      u16 hh = f2bf(v); float hf = __uint_as_float(((u32)hh)<<16);
      u16 ll = f2bf(v - hf);
      phiH[h*64 + d] = hh; phiL[h*64 + d] = ll;
    }
  }
}

// ---------- K-FUSED (1024 threads / 16 waves, 1 block/CU -> VGPR cap 128, no spill) ----------
// grid 512 (1 batch/block). 2 passes; pass p: wave w handles unit (g = 8p + (w>>1), ch = w&1).
// Even waves compute the shared Y row-group; all waves score their 16x128 half (kv[32]).
__global__ __launch_bounds__(1024, 4) void k_fused(
    const float* __restrict__ x, const u16* __restrict__ MtH, const u16* __restrict__ MtL,
    const float* __restrict__ uvc,
    u64* __restrict__ cand, int* __restrict__ cand_n)
{
  extern __shared__ __align__(16) u16 smem[];
  u16* XH = smem;                       // [256][72]
  u16* XL = XH + 256*72;                // [256][72]
  u16* YH = XL + 256*72;                // [128][72] (8 row-groups per pass)
  u16* YL = YH + 128*72;
  float* STS = (float*)(YL + 128*72);   // [256] s_i + c (pad -> -1e38)
  float* STT = STS + 256;               // [256] t_j   (pad -> -1e38)
  float* SUV = STT + 256;               // [132]

  int tid = threadIdx.x;
  int b = blockIdx.x;
  const float* xb = x + (size_t)b*(L_SEQ*D_IN);

  if (tid < 129) SUV[tid] = uvc[tid];

  // ---- Phase A: load + split x into LDS (1 quarter-row per thread) ----
  int r = tid >> 2, q = tid & 3;
  float v[16];
  {
    const float* xr = xb + (size_t)r*D_IN + q*16;
    #pragma unroll
    for (int i=0;i<4;++i) *(float4*)&v[i*4] = *(const float4*)(xr + i*4);
    u32 hpA[4],lpA[4],hpB[4],lpB[4];
    cvt8(&v[0], hpA, lpA); cvt8(&v[8], hpB, lpB);
    u16* dh = XH + r*72 + q*16;
    u16* dl = XL + r*72 + q*16;
    *(uint4*)(dh)     = make_uint4(hpA[0],hpA[1],hpA[2],hpA[3]);
    *(uint4*)(dh + 8) = make_uint4(hpB[0],hpB[1],hpB[2],hpB[3]);
    *(uint4*)(dl)     = make_uint4(lpA[0],lpA[1],lpA[2],lpA[3]);
    *(uint4*)(dl + 8) = make_uint4(lpB[0],lpB[1],lpB[2],lpB[3]);
  }
  // s_i, t_j, pad (r7 summation tree)
  {
    float su=0.f, tv=0.f, pa=0.f;
    #pragma unroll
    for (int d=0; d<16; ++d){
      float xa = v[d];
      su = fmaf(xa, SUV[q*16+d], su);
      tv = fmaf(xa, SUV[64+q*16+d], tv);
      pa += fabsf(xa);
    }
    su += __shfl_xor(su,1); su += __shfl_xor(su,2);
    tv += __shfl_xor(tv,1); tv += __shfl_xor(tv,2);
    pa += __shfl_xor(pa,1); pa += __shfl_xor(pa,2);
    if (q == 0){
      bool pad = (pa != 0.f);
      STS[r] = pad ? (su + SUV[128]) : -1e38f;
      STT[r] = pad ? tv : -1e38f;
    }
  }
  __syncthreads();   // SUV/X/STS/STT visible

  int w = tid >> 6, lane = tid & 63, lm = lane & 15, quad = lane >> 4;
  int gb = w >> 1, ch = w & 1;

  for (int p=0; p<2; ++p){
    int g = 8*p + gb;
    int r0 = g*16;

    // ---- y = x M for this row-group (even waves only) ----
    if (ch == 0){
      const u16* ah = XH + (r0+lm)*72;
      const u16* al = XL + (r0+lm)*72;
      bf16x8 Ah0 = *(const bf16x8*)(ah + quad*8);
      bf16x8 Ah1 = *(const bf16x8*)(ah + 32 + quad*8);
      bf16x8 Al0 = *(const bf16x8*)(al + quad*8);
      bf16x8 Al1 = *(const bf16x8*)(al + 32 + quad*8);
      #pragma unroll
      for (int ct=0; ct<4; ++ct){
        const u16* mth = MtH + (ct*16+lm)*64 + quad*8;
        const u16* mtl = MtL + (ct*16+lm)*64 + quad*8;
        bf16x8 Bh0 = *(const bf16x8*)(mth);
        bf16x8 Bh1 = *(const bf16x8*)(mth + 32);
        bf16x8 Bl0 = *(const bf16x8*)(mtl);
        bf16x8 Bl1 = *(const bf16x8*)(mtl + 32);
        f32x4 a1 = {0.f,0.f,0.f,0.f}, a2 = {0.f,0.f,0.f,0.f};
        a1 = __builtin_amdgcn_mfma_f32_16x16x32_bf16(Ah0, Bh0, a1, 0,0,0);
        a2 = __builtin_amdgcn_mfma_f32_16x16x32_bf16(Ah1, Bh1, a2, 0,0,0);
        a1 = __builtin_amdgcn_mfma_f32_16x16x32_bf16(Al0, Bh0, a1, 0,0,0);
        a2 = __builtin_amdgcn_mfma_f32_16x16x32_bf16(Al1, Bh1, a2, 0,0,0);
        a1 = __builtin_amdgcn_mfma_f32_16x16x32_bf16(Ah0, Bl0, a1, 0,0,0);
        a2 = __builtin_amdgcn_mfma_f32_16x16x32_bf16(Ah1, Bl1, a2, 0,0,0);
        #pragma unroll
        for (int rg=0; rg<4; ++rg){
          float vy = a1[rg] + a2[rg];
          u16 hh = f2bf(vy); float hf = __uint_as_float(((u32)hh)<<16);
          u16 ll = f2bf(vy - hf);
          YH[(gb*16 + quad*4 + rg)*72 + ct*16 + lm] = hh;
          YL[(gb*16 + quad*4 + rg)*72 + ct*16 + lm] = ll;
        }
      }
    }
    __syncthreads();   // Y visible to odd waves

    // ---- scores for own 16x128 half ----
    const u16* yh_ = YH + (gb*16+lm)*72;
    const u16* yl_ = YL + (gb*16+lm)*72;
    bf16x8 Yh0 = *(const bf16x8*)(yh_ + quad*8);
    bf16x8 Yh1 = *(const bf16x8*)(yh_ + 32 + quad*8);
    bf16x8 Yl0 = *(const bf16x8*)(yl_ + quad*8);
    bf16x8 Yl1 = *(const bf16x8*)(yl_ + 32 + quad*8);

    float sr[4];
    #pragma unroll
    for (int rr=0;rr<4;++rr) sr[rr] = STS[r0 + quad*4 + rr];

    int j0 = ch*128;
    u32 kv[32];
    #pragma unroll
    for (int ct=0; ct<8; ++ct){
      const u16* bh = XH + (j0 + ct*16+lm)*72;
      const u16* bl = XL + (j0 + ct*16+lm)*72;
      bf16x8 Bh0 = *(const bf16x8*)(bh + quad*8);
      bf16x8 Bh1 = *(const bf16x8*)(bh + 32 + quad*8);
      bf16x8 Bl0 = *(const bf16x8*)(bl + quad*8);
      bf16x8 Bl1 = *(const bf16x8*)(bl + 32 + quad*8);
      f32x4 a1 = {0.f,0.f,0.f,0.f}, a2 = {0.f,0.f,0.f,0.f};
      a1 = __builtin_amdgcn_mfma_f32_16x16x32_bf16(Yh0, Bh0, a1, 0,0,0);
      a2 = __builtin_amdgcn_mfma_f32_16x16x32_bf16(Yh1, Bh1, a2, 0,0,0);
      a1 = __builtin_amdgcn_mfma_f32_16x16x32_bf16(Yl0, Bh0, a1, 0,0,0);
      a2 = __builtin_amdgcn_mfma_f32_16x16x32_bf16(Yl1, Bh1, a2, 0,0,0);
      a1 = __builtin_amdgcn_mfma_f32_16x16x32_bf16(Yh0, Bl0, a1, 0,0,0);
      a2 = __builtin_amdgcn_mfma_f32_16x16x32_bf16(Yh1, Bl1, a2, 0,0,0);
      float tc = STT[j0 + ct*16 + lm];
      #pragma unroll
      for (int rr=0;rr<4;++rr)
        kv[ct*4 + rr] = sortKey(a1[rr] + a2[rr] + sr[rr] + tc);
    }

    // 16-bit-prefix threshold, early-exit in [TOPK, CAP]
    u32 T = 0;
    for (int bit=15; bit>=0; --bit){
      u32 th2 = (T | (1u<<bit)) << 16;
      int c = 0;
      #pragma unroll
      for (int i=0;i<32;++i)
        c += (int)__popcll(__ballot(kv[i] >= th2));
      if (c >= TOPK){
        T |= (1u<<bit);
        if (c <= CAP) break;
      }
    }
    u32 thr = T << 16;
    u32 up  = (T < 0xffffu) ? ((T+1u) << 16) : 0xffffffffu;

    // two-class emission: above-bucket first, then T-bucket
    u32 m1 = 0, m2 = 0;
    #pragma unroll
    for (int i=0;i<32;++i){
      bool ge = kv[i] >= thr;
      bool c1 = ge && (kv[i] >= up);
      m1 |= (c1 ? 1u : 0u) << i;
      m2 |= ((ge && !c1) ? 1u : 0u) << i;
    }
    int n1 = __popc(m1), n2 = __popc(m2);
    int p1 = n1, p2 = n2;
    #pragma unroll
    for (int off=1; off<64; off<<=1){
      int a = __shfl_up(p1, off); if (lane >= off) p1 += a;
      int c = __shfl_up(p2, off); if (lane >= off) p2 += c;
    }
    int tot1 = __shfl(p1, 63), tot2 = __shfl(p2, 63);
    int pos1 = p1 - n1;
    int pos2 = tot1 + (p2 - n2);
    int total = tot1 + tot2;
    int wt = g*2 + ch;
    size_t base = ((size_t)b*NWT + wt)*CAP;
    if (lane == 0) cand_n[b*NWT + wt] = (total < CAP) ? total : CAP;
    while (m1){
      int i = __ffs(m1) - 1; m1 &= m1 - 1;
      if (pos1 < CAP){
        int rr = i & 3, ct = i >> 2;
        int flat = (r0 + quad*4 + rr)*L_SEQ + (j0 + ct*16 + lm);
        cand[base + pos1] = ((u64)kv[i] << 32) | (u32)flat;
      }
      ++pos1;
    }
    while (m2){
      int i = __ffs(m2) - 1; m2 &= m2 - 1;
      if (pos2 < CAP){
        int rr = i & 3, ct = i >> 2;
        int flat = (r0 + quad*4 + rr)*L_SEQ + (j0 + ct*16 + lm);
        cand[base + pos2] = ((u64)kv[i] << 32) | (u32)flat;
      }
      ++pos2;
    }
    __syncthreads();   // Y buffer reuse in next pass
  }
}

// ---------- FALLBACK K1: split x; st; y via MFMA ----------
__global__ __launch_bounds__(256) void k_pre(
    const float* __restrict__ x, const u16* __restrict__ MtH, const u16* __restrict__ MtL,
    const float* __restrict__ uvc,
    u16* __restrict__ xh, u16* __restrict__ xl,
    u16* __restrict__ yh, u16* __restrict__ yl,
    float* __restrict__ st)
{
  __shared__ __align__(16) u16 sh[64][72];
  __shared__ __align__(16) u16 sl[64][72];
  __shared__ float sUV[132];
  int tid = threadIdx.x;
  int g0 = blockIdx.x * 64;
  int b  = g0 >> 8, l0 = g0 & 255;
  int r = tid >> 2, q = tid & 3;

  if (tid < 129) sUV[tid] = uvc[tid];

  float v[16];
  {
    const float* xr = x + (size_t)(g0 + r)*D_IN + q*16;
    #pragma unroll
    for (int i=0;i<4;++i) *(float4*)&v[i*4] = *(const float4*)(xr + i*4);
  }
  {
    u32 hpA[4],lpA[4],hpB[4],lpB[4];
    cvt8(&v[0], hpA, lpA); cvt8(&v[8], hpB, lpB);
    size_t xo = (size_t)(g0 + r)*D_IN + q*16;
    *(uint4*)(xh + xo)     = make_uint4(hpA[0],hpA[1],hpA[2],hpA[3]);
    *(uint4*)(xh + xo + 8) = make_uint4(hpB[0],hpB[1],hpB[2],hpB[3]);
    *(uint4*)(xl + xo)     = make_uint4(lpA[0],lpA[1],lpA[2],lpA[3]);
    *(uint4*)(xl + xo + 8) = make_uint4(lpB[0],lpB[1],lpB[2],lpB[3]);
    *(uint4*)&sh[r][q*16]   = make_uint4(hpA[0],hpA[1],hpA[2],hpA[3]);
    *(uint4*)&sh[r][q*16+8] = make_uint4(hpB[0],hpB[1],hpB[2],hpB[3]);
    *(uint4*)&sl[r][q*16]   = make_uint4(lpA[0],lpA[1],lpA[2],lpA[3]);
    *(uint4*)&sl[r][q*16+8] = make_uint4(lpB[0],lpB[1],lpB[2],lpB[3]);
  }
  __syncthreads();

  {
    float su=0.f, tv=0.f, pa=0.f;
    #pragma unroll
    for (int d=0; d<16; ++d){
      float xa = v[d];
      su = fmaf(xa, sUV[q*16+d], su);
      tv = fmaf(xa, sUV[64+q*16+d], tv);
      pa += fabsf(xa);
    }
    su += __shfl_xor(su,1); su += __shfl_xor(su,2);
    tv += __shfl_xor(tv,1); tv += __shfl_xor(tv,2);
    pa += __shfl_xor(pa,1); pa += __shfl_xor(pa,2);
    if (q == 0){
      bool pad = (pa != 0.f);
      st[(size_t)b*L_SEQ + l0 + r]          = pad ? (su + sUV[128]) : -1e38f;
      st[(size_t)(B_TOT+b)*L_SEQ + l0 + r]  = pad ? tv : -1e38f;
    }
  }

  int w = tid >> 6, lane = tid & 63, lm = lane & 15, quad = lane >> 4;
  bf16x8 Ah0 = *(const bf16x8*)&sh[w*16+lm][quad*8];
  bf16x8 Ah1 = *(const bf16x8*)&sh[w*16+lm][32 + quad*8];
  bf16x8 Al0 = *(const bf16x8*)&sl[w*16+lm][quad*8];
  bf16x8 Al1 = *(const bf16x8*)&sl[w*16+lm][32 + quad*8];
  #pragma unroll
  for (int ct=0; ct<4; ++ct){
    const u16* mth = MtH + (ct*16+lm)*64 + quad*8;
    const u16* mtl = MtL + (ct*16+lm)*64 + quad*8;
    bf16x8 Bh0 = *(const bf16x8*)(mth);
    bf16x8 Bh1 = *(const bf16x8*)(mth + 32);
    bf16x8 Bl0 = *(const bf16x8*)(mtl);
    bf16x8 Bl1 = *(const bf16x8*)(mtl + 32);
    f32x4 a1 = {0.f,0.f,0.f,0.f}, a2 = {0.f,0.f,0.f,0.f};
    a1 = __builtin_amdgcn_mfma_f32_16x16x32_bf16(Ah0, Bh0, a1, 0,0,0);
    a2 = __builtin_amdgcn_mfma_f32_16x16x32_bf16(Ah1, Bh1, a2, 0,0,0);
    a1 = __builtin_amdgcn_mfma_f32_16x16x32_bf16(Al0, Bh0, a1, 0,0,0);
    a2 = __builtin_amdgcn_mfma_f32_16x16x32_bf16(Al1, Bh1, a2, 0,0,0);
    a1 = __builtin_amdgcn_mfma_f32_16x16x32_bf16(Ah0, Bl0, a1, 0,0,0);
    a2 = __builtin_amdgcn_mfma_f32_16x16x32_bf16(Ah1, Bl1, a2, 0,0,0);
    #pragma unroll
    for (int rg=0; rg<4; ++rg){
      float vy = a1[rg] + a2[rg];
      u16 hh = f2bf(vy); float hf = __uint_as_float(((u32)hh)<<16);
      u16 ll = f2bf(vy - hf);
      sh[w*16 + quad*4 + rg][ct*16 + lm] = hh;
      sl[w*16 + quad*4 + rg][ct*16 + lm] = ll;
    }
  }
  {
    size_t yo = (size_t)(g0 + r)*D_IN + q*16;
    *(uint4*)(yh + yo)     = *(uint4*)&sh[r][q*16];
    *(uint4*)(yh + yo + 8) = *(uint4*)&sh[r][q*16+8];
    *(uint4*)(yl + yo)     = *(uint4*)&sl[r][q*16];
    *(uint4*)(yl + yo + 8) = *(uint4*)&sl[r][q*16+8];
  }
}

// ---------- FALLBACK K2: k_score (r7) ----------
__global__ __launch_bounds__(256) void k_score(
    const u16* __restrict__ xh, const u16* __restrict__ xl,
    const u16* __restrict__ yh, const u16* __restrict__ yl,
    const float* __restrict__ st,
    u64* __restrict__ cand, int* __restrict__ cand_n)
{
  int tid = threadIdx.x;
  int lin = blockIdx.x;
  int b    = ((lin >> 6) << 3) | (lin & 7);
  int tile = (lin >> 3) & 7;
  int cb = tile & 1, rb = tile >> 1;
  int r0 = rb*64, j0 = cb*128;
  int w = tid >> 6, lane = tid & 63, lm = lane & 15, quad = lane >> 4;

  size_t rowA = ((size_t)b*L_SEQ + r0 + w*16 + lm)*D_IN;
  bf16x8 A_h0 = *(const bf16x8*)(yh + rowA + quad*8);
  bf16x8 A_h1 = *(const bf16x8*)(yh + rowA + 32 + quad*8);
  bf16x8 A_l0 = *(const bf16x8*)(yl + rowA + quad*8);
  bf16x8 A_l1 = *(const bf16x8*)(yl + rowA + 32 + quad*8);

  float4 s4 = *(const float4*)(st + (size_t)b*L_SEQ + r0 + w*16 + quad*4);
  float sr[4] = {s4.x, s4.y, s4.z, s4.w};
  float tc[8];
  #pragma unroll
  for (int ct=0;ct<8;++ct)
    tc[ct] = st[(size_t)(B_TOT + b)*L_SEQ + j0 + ct*16 + lm];

  u32 kv[32];
  #pragma unroll
  for (int ct=0; ct<8; ++ct){
    size_t rowB = ((size_t)b*L_SEQ + j0 + ct*16 + lm)*D_IN;
    bf16x8 B_h0 = *(const bf16x8*)(xh + rowB + quad*8);
    bf16x8 B_h1 = *(const bf16x8*)(xh + rowB + 32 + quad*8);
    bf16x8 B_l0 = *(const bf16x8*)(xl + rowB + quad*8);
    bf16x8 B_l1 = *(const bf16x8*)(xl + rowB + 32 + quad*8);
    f32x4 a1 = {0.f,0.f,0.f,0.f}, a2 = {0.f,0.f,0.f,0.f};
    a1 = __builtin_amdgcn_mfma_f32_16x16x32_bf16(A_h0, B_h0, a1, 0,0,0);
    a2 = __builtin_amdgcn_mfma_f32_16x16x32_bf16(A_h1, B_h1, a2, 0,0,0);
    a1 = __builtin_amdgcn_mfma_f32_16x16x32_bf16(A_l0, B_h0, a1, 0,0,0);
    a2 = __builtin_amdgcn_mfma_f32_16x16x32_bf16(A_l1, B_h1, a2, 0,0,0);
    a1 = __builtin_amdgcn_mfma_f32_16x16x32_bf16(A_h0, B_l0, a1, 0,0,0);
    a2 = __builtin_amdgcn_mfma_f32_16x16x32_bf16(A_h1, B_l1, a2, 0,0,0);
    #pragma unroll
    for (int r=0;r<4;++r)
      kv[ct*4 + r] = sortKey(a1[r] + a2[r] + sr[r] + tc[ct]);
  }

  u32 T = 0;
  for (int bit=15; bit>=0; --bit){
    u32 th2 = (T | (1u<<bit)) << 16;
    int c = 0;
    #pragma unroll
    for (int i=0;i<32;++i)
      c += (int)__popcll(__ballot(kv[i] >= th2));
    if (c >= TOPK){
      T |= (1u<<bit);
      if (c <= CAP) break;
    }
  }
  u32 thr = T << 16;

  u32 hm = 0;
  #pragma unroll
  for (int i=0;i<32;++i) hm |= (kv[i] >= thr ? 1u : 0u) << i;
  int myc = __popc(hm);
  int pre = myc;
  #pragma unroll
  for (int off=1; off<64; off<<=1){
    int n = __shfl_up(pre, off);
    if (lane >= off) pre += n;
  }
  int total = __shfl(pre, 63);
  int pos = pre - myc;
  int wt = tile*4 + w;
  size_t base = ((size_t)b*NWT + wt)*CAP;
  if (lane == 0) cand_n[b*NWT + wt] = (total < CAP) ? total : CAP;
  while (hm){
    int i = __ffs(hm) - 1; hm &= hm - 1;
    if (pos < CAP){
      int r = i & 3, ct = i >> 2;
      int flat = (r0 + w*16 + quad*4 + r)*L_SEQ + (j0 + ct*16 + lm);
      cand[base + pos] = ((u64)kv[i] << 32) | (u32)flat;
    }
    ++pos;
  }
}

// ---------- K3: fused merge + MLP (merge scratch aliased over AF gather buffers) ----------
__global__ __launch_bounds__(256) void k_mergemlp(
    const u64* __restrict__ cand, const int* __restrict__ cand_n,
    const float* __restrict__ x,
    const u16* __restrict__ xiH, const u16* __restrict__ xiL,
    const u16* __restrict__ phiH, const u16* __restrict__ phiL,
    const float* __restrict__ phi_b1, const float* __restrict__ phi_w2, const float* __restrict__ phi_b2,
    const float* __restrict__ xi_b1,  const float* __restrict__ xi_w2,  const float* __restrict__ xi_b2,
    const float* __restrict__ rho_w1, const float* __restrict__ rho_b1,
    const float* __restrict__ rho_w2, const float* __restrict__ rho_b2,
    float* __restrict__ out)
{
  __shared__ __align__(16) u8 regA[65536];
  // merge-phase views (all < 32 KB)
  u64*   wbuf = (u64*)regA;                 // [4][192]
  int*   eqi  = (int*)(regA + 6144);        // [256]
  float* sv   = (float*)(regA + 7168);      // [128]
  int*   si   = (int*)(regA + 7680);        // [128]
  int*   scnt = (int*)(regA + 8192);        // [32]
  int*   wcnt = (int*)(regA + 8320);        // [4]
  float* fred = (float*)(regA + 8336);      // [8]
  int*   cms  = (int*)(regA + 8368);        // cm, eqc
  // mlp-phase views
  u16* AFh = (u16*)regA;                    // [8][4][64][8] = 32768 B
  u16* AFl = (u16*)(regA + 32768);
  // persistent
  __shared__ int   sidx[TOPK];
  __shared__ float swp[TOPK], swd[TOPK];
  __shared__ float gpL[256], gsL[256];
  __shared__ float pooled[256], t1[256];
  __shared__ float wsums[2];

  int b = blockIdx.x, tid = threadIdx.x;
  int w = tid >> 6, lane = tid & 63;

  // ===== merge phase =====
  const int SL   = NWT/4;           // 8 slots per wave
  const int NSW  = SL*CAP/64;       // 20 keys per lane
  const int WCAP = 192;
  if (tid < NWT) scnt[tid] = cand_n[b*NWT + tid];
  if (tid == 0){ cms[0] = 0; cms[1] = 0; }
  __syncthreads();

  {
    u32 key[NSW]; int idx[NSW];
    size_t bb = (size_t)b*NWT*CAP + (size_t)(w*SL)*CAP;
    #pragma unroll
    for (int s=0;s<NSW;++s){
      int e = lane + 64*s;
      int slot = e / CAP, p = e - slot*CAP;
      bool ok = p < scnt[w*SL + slot];
      u64 v = ok ? cand[bb + e] : 0ull;
      key[s] = (u32)(v >> 32);
      idx[s] = ok ? (int)(u32)v : 0x7fffffff;
    }

    u32 T = 0;
    for (int bit=31; bit>=0; --bit){
      u32 c2 = T | (1u<<bit);
      int c = 0;
      #pragma unroll
      for (int s=0;s<NSW;++s) c += (int)__popcll(__ballot(key[s] >= c2));
      if (c >= TOPK){
        T = c2;
        if (c <= WCAP) break;
      }
    }
    int myc = 0;
    #pragma unroll
    for (int s=0;s<NSW;++s) myc += (key[s] >= T) ? 1 : 0;
    int pre = myc;
    #pragma unroll
    for (int off=1; off<64; off<<=1){
      int n = __shfl_up(pre, off);
      if (lane >= off) pre += n;
    }
    int total = __shfl(pre, 63);
    int pos = pre - myc;
    if (lane == 0) wcnt[w] = (total < WCAP) ? total : WCAP;
    #pragma unroll
    for (int s=0;s<NSW;++s){
      if (key[s] >= T){
        if (pos < WCAP) wbuf[w*WCAP + pos] = ((u64)key[s] << 32) | (u32)idx[s];
        ++pos;
      }
    }
  }
  __syncthreads();

  if (w == 0){
    const int NS2 = 4*192/64;   // 12
    u32 k2[NS2]; int i2[NS2];
    #pragma unroll
    for (int s=0;s<NS2;++s){
      int e = lane + 64*s;
      int slot = e / WCAP, p = e - slot*WCAP;
      bool ok = p < wcnt[slot];
      u64 v = ok ? wbuf[slot*WCAP + p] : 0ull;
      k2[s] = (u32)(v >> 32);
      i2[s] = ok ? (int)(u32)v : 0x7fffffff;
    }
    u32 T2 = 0;
    for (int bit=31; bit>=0; --bit){
      u32 c2 = T2 | (1u<<bit);
      int c = 0;
      #pragma unroll
      for (int s=0;s<NS2;++s) c += (int)__popcll(__ballot(k2[s] >= c2));
      if (c >= TOPK) T2 = c2;
    }
    int m = 0;
    #pragma unroll
    for (int s=0;s<NS2;++s) m += (int)__popcll(__ballot(k2[s] > T2));
    #pragma unroll
    for (int s=0;s<NS2;++s){
      if (k2[s] > T2){
        int p = atomicAdd(&cms[0], 1);
        sv[p] = unKey(k2[s]) * 0.0625f; si[p] = i2[s];
      } else if (k2[s] == T2 && i2[s] != 0x7fffffff){
        int q = atomicAdd(&cms[1], 1);
        if (q < 256) eqi[q] = i2[s];
      }
    }
    if (lane == 0){
      int need = TOPK - m;
      int n = cms[1] < 256 ? cms[1] : 256;
      float tv = unKey(T2) * 0.0625f;
      for (int s2=0; s2<need; ++s2){
        int bi = s2;
        for (int j=s2+1;j<n;++j) if (eqi[j] < eqi[bi]) bi = j;
        int t2 = eqi[s2]; eqi[s2] = eqi[bi]; eqi[bi] = t2;
        sv[m+s2] = tv; si[m+s2] = eqi[s2];
      }
    }
  }
  __syncthreads();

  // softmax + weight classification (into persistent LDS)
  {
    float v = (tid < TOPK) ? sv[tid] : -3.4e38f;
    float mx = v;
    #pragma unroll
    for (int off=1; off<64; off<<=1) mx = fmaxf(mx, __shfl_xor(mx, off));
    if ((tid&63)==0) fred[tid>>6] = mx;
    __syncthreads();
    mx = fmaxf(fred[0], fred[1]);
    float e = (tid < TOPK) ? expf(v - mx) : 0.f;
    float s = e;
    #pragma unroll
    for (int off=1; off<64; off<<=1) s += __shfl_xor(s, off);
    if ((tid&63)==0) fred[4 + (tid>>6)] = s;
    __syncthreads();
    s = fred[4] + fred[5];
    if (tid < TOPK){
      float wv = e / s;
      int fl = si[tid];
      sidx[tid] = fl;
      bool dg = ((fl>>8) == (fl&255));
      swp[tid] = dg ? 0.f : wv;
      swd[tid] = dg ? wv  : 0.f;
    }
  }
  __syncthreads();   // merge scratch dead; AF writes may begin
  if (tid == 0){
    float a=0.f, c2=0.f;
    for (int k=0;k<TOPK;++k){ a+=swp[k]; c2+=swd[k]; }
    wsums[0]=a; wsums[1]=c2;
  }

  // ===== gather + split into fragment-order AF =====
  {
    int m = tid >> 1, hf = tid & 1;
    int fl = sidx[m];
    int rc = hf ? (fl & 255) : (fl >> 8);
    const float* src = x + ((size_t)b*L_SEQ + rc)*D_IN;
    int kt = m >> 4, l16 = m & 15;
    #pragma unroll
    for (int g=0; g<8; ++g){
      int d0 = hf*64 + g*8;
      int c = d0 >> 5, q = (d0 >> 3) & 3;
      float v[8];
      *(float4*)&v[0] = *(const float4*)(src + (d0 & 63));
      *(float4*)&v[4] = *(const float4*)(src + (d0 & 63) + 4);
      u32 hp[4], lp[4];
      cvt8(v, hp, lp);
      *(uint4*)&AFh[(((kt*4 + c)*64) + (l16 + 16*q))*8] = make_uint4(hp[0],hp[1],hp[2],hp[3]);
      *(uint4*)&AFl[(((kt*4 + c)*64) + (l16 + 16*q))*8] = make_uint4(lp[0],lp[1],lp[2],lp[3]);
    }
  }
  __syncthreads();

  int lm = lane & 15, quad = lane >> 4;

  #pragma unroll
  for (int hi4=0; hi4<4; ++hi4){
    int ht = w + 4*hi4;
    int h  = ht*16 + lm;
    bf16x8 BXh[4], BXl[4], BPh[2], BPl[2];
    #pragma unroll
    for (int c=0;c<4;++c){
      BXh[c] = *(const bf16x8*)(xiH + h*128 + c*32 + quad*8);
      BXl[c] = *(const bf16x8*)(xiL + h*128 + c*32 + quad*8);
    }
    #pragma unroll
    for (int c=0;c<2;++c){
      BPh[c] = *(const bf16x8*)(phiH + h*64 + c*32 + quad*8);
      BPl[c] = *(const bf16x8*)(phiL + h*64 + c*32 + quad*8);
    }
    float bxi = xi_b1[h], bph = phi_b1[h];
    float gp = 0.f, gs = 0.f;
    for (int kt=0; kt<8; ++kt){
      bf16x8 Ah_[4], Al_[4];
      #pragma unroll
      for (int c=0;c<4;++c){
        Ah_[c] = *(const bf16x8*)&AFh[(((kt*4 + c)*64) + lane)*8];
        Al_[c] = *(const bf16x8*)&AFl[(((kt*4 + c)*64) + lane)*8];
      }
      f32x4 cx = {0.f,0.f,0.f,0.f}, cp = {0.f,0.f,0.f,0.f};
      #pragma unroll
      for (int c=0;c<4;++c){
        cx = __builtin_amdgcn_mfma_f32_16x16x32_bf16(Ah_[c], BXh[c], cx, 0,0,0);
        cx = __builtin_amdgcn_mfma_f32_16x16x32_bf16(Al_[c], BXh[c], cx, 0,0,0);
        cx = __builtin_amdgcn_mfma_f32_16x16x32_bf16(Ah_[c], BXl[c], cx, 0,0,0);
      }
      #pragma unroll
      for (int c=0;c<2;++c){
        cp = __builtin_amdgcn_mfma_f32_16x16x32_bf16(Ah_[c], BPh[c], cp, 0,0,0);
        cp = __builtin_amdgcn_mfma_f32_16x16x32_bf16(Al_[c], BPh[c], cp, 0,0,0);
        cp = __builtin_amdgcn_mfma_f32_16x16x32_bf16(Ah_[c], BPl[c], cp, 0,0,0);
      }
      #pragma unroll
      for (int r=0;r<4;++r){
        int kk = kt*16 + quad*4 + r;
        gp = fmaf(swp[kk], fmaxf(cx[r] + bxi, 0.f), gp);
        gs = fmaf(swd[kk], fmaxf(cp[r] + bph, 0.f), gs);
      }
    }
    gp += __shfl_xor(gp, 16); gp += __shfl_xor(gp, 32);
    gs += __shfl_xor(gs, 16); gs += __shfl_xor(gs, 32);
    if (quad == 0){ gpL[h] = gp; gsL[h] = gs; }
  }
  __syncthreads();

  int h = tid;
  {
    float wsp = wsums[0], wss = wsums[1];
    float po = wsp*xi_b2[h] + wss*phi_b2[h];
    for (int d=0; d<256; ++d){
      po = fmaf(gpL[d], xi_w2[d*HIDN + h], po);
      po = fmaf(gsL[d], phi_w2[d*HIDN + h], po);
    }
    pooled[h] = po;
  }
  __syncthreads();
  {
    float a = rho_b1[h];
    for (int d=0; d<256; ++d) a = fmaf(pooled[d], rho_w1[d*HIDN + h], a);
    t1[h] = fmaxf(a, 0.f);
  }
  __syncthreads();
  if (h < 128){
    float o = rho_b2[h];
    for (int d=0; d<256; ++d) o = fmaf(t1[d], rho_w2[d*128 + h], o);
    out[(size_t)b*128 + h] = o;
  }
}

// ---------- host ----------
extern "C" void kernel_launch(void* const* d_in, const int* in_sizes, int n_in,
                              void* d_out, int out_size, void* d_ws, size_t ws_size,
                              hipStream_t stream)
{
  (void)in_sizes; (void)n_in; (void)out_size; (void)ws_size;
  const float* x      = (const float*)d_in[0];
  const float* Wq     = (const float*)d_in[1];
  const float* bq     = (const float*)d_in[2];
  const float* Wk     = (const float*)d_in[3];
  const float* bk     = (const float*)d_in[4];
  const float* phi_w1 = (const float*)d_in[5];
  const float* phi_b1 = (const float*)d_in[6];
  const float* phi_w2 = (const float*)d_in[7];
  const float* phi_b2 = (const float*)d_in[8];
  const float* xi_w1  = (const float*)d_in[9];
  const float* xi_b1  = (const float*)d_in[10];
  const float* xi_w2  = (const float*)d_in[11];
  const float* xi_b2  = (const float*)d_in[12];
  const float* rho_w1 = (const float*)d_in[13];
  const float* rho_b1 = (const float*)d_in[14];
  const float* rho_w2 = (const float*)d_in[15];
  const float* rho_b2 = (const float*)d_in[16];
  float* out = (float*)d_out;

  const size_t NX = (size_t)B_TOT*L_SEQ*D_IN;      // 8,388,608
  float* uvc    = (float*)d_ws;                    // 256
  float* st     = uvc + 256;                       // 2*512*256
  float* selw   = st + (size_t)2*B_TOT*L_SEQ;      // (unused, layout kept)
  int*   selidx = (int*)(selw + (size_t)B_TOT*TOPK);
  int*   cand_n = selidx + (size_t)B_TOT*TOPK;     // 512*32
  u64*   cand   = (u64*)(cand_n + (size_t)B_TOT*NWT);
  u16*   MtH    = (u16*)(cand + (size_t)B_TOT*NWT*CAP);
  u16*   MtL    = MtH + 64*64;
  u16*   xiH    = MtL + 64*64;
  u16*   xiL    = xiH + 256*128;
  u16*   phiH   = xiL + 256*128;
  u16*   phiL   = phiH + 256*64;
  u16*   xh     = phiL + 256*64;
  u16*   xl     = xh + NX;
  u16*   yh     = xl + NX;
  u16*   yl     = yh + NX;

  // deterministic per-device check (same result every call -> graph-safe)
  hipError_t aerr = hipFuncSetAttribute((const void*)k_fused,
                      hipFuncAttributeMaxDynamicSharedMemorySize, FLDS);

  k_wprep<<<dim3(256),  dim3(256), 0, stream>>>(Wq, bq, Wk, bk, xi_w1, phi_w1,
                                                MtH, MtL, uvc, xiH, xiL, phiH, phiL);
  if (aerr == hipSuccess){
    k_fused<<<dim3(B_TOT), dim3(1024), FLDS, stream>>>(x, MtH, MtL, uvc, cand, cand_n);
  } else {
    k_pre  <<<dim3(2048), dim3(256), 0, stream>>>(x, MtH, MtL, uvc, xh, xl, yh, yl, st);
    k_score<<<dim3(4096), dim3(256), 0, stream>>>(xh, xl, yh, yl, st, cand, cand_n);
  }
  k_mergemlp<<<dim3(B_TOT), dim3(256), 0, stream>>>(cand, cand_n, x,
            xiH, xiL, phiH, phiL,
            phi_b1, phi_w2, phi_b2,
            xi_b1, xi_w2, xi_b2,
            rho_w1, rho_b1, rho_w2, rho_b2, out);
}

// Round 13
// 290.517 us; speedup vs baseline: 1.1173x; 1.1173x over previous
//
#include <hip/hip_runtime.h>

typedef unsigned short u16;
typedef unsigned int   u32;
typedef unsigned char  u8;
typedef unsigned long long u64;

#define B_TOT 512
#define L_SEQ 256
#define D_IN  64
#define HIDN  256
#define TOPK  128
#define CAP   160              // candidate cap per unit
#define NWT   32               // units per batch
#define FLDS  113280           // fused dynamic LDS bytes

typedef float  f32x4  __attribute__((ext_vector_type(4)));
typedef __bf16 bf16x8 __attribute__((ext_vector_type(8)));

// ---------- helpers ----------
__device__ __forceinline__ u16 f2bf(float f){
  u32 u = __float_as_uint(f);
  u32 r = u + 0x7fffu + ((u>>16)&1u);   // RNE
  return (u16)(r>>16);
}
__device__ __forceinline__ u32 sortKey(float f){
  u32 b = __float_as_uint(f);
  return (b & 0x80000000u) ? ~b : (b | 0x80000000u);
}
__device__ __forceinline__ float unKey(u32 u){
  u32 b = (u & 0x80000000u) ? (u & 0x7fffffffu) : ~u;
  return __uint_as_float(b);
}
__device__ __forceinline__ void cvt8(const float* v, u32* hp, u32* lp){
  #pragma unroll
  for (int i=0;i<4;++i){
    float v0 = v[2*i], v1 = v[2*i+1];
    u16 h0 = f2bf(v0); float h0f = __uint_as_float(((u32)h0)<<16); u16 l0 = f2bf(v0 - h0f);
    u16 h1 = f2bf(v1); float h1f = __uint_as_float(((u32)h1)<<16); u16 l1 = f2bf(v1 - h1f);
    hp[i] = (u32)h0 | ((u32)h1<<16);
    lp[i] = (u32)l0 | ((u32)l1<<16);
  }
}

// ---------- K0: fused weight prep ----------
__global__ __launch_bounds__(256) void k_wprep(
    const float* __restrict__ Wq, const float* __restrict__ bq,
    const float* __restrict__ Wk, const float* __restrict__ bk,
    const float* __restrict__ xi_w1, const float* __restrict__ phi_w1,
    u16* __restrict__ MtH, u16* __restrict__ MtL, float* __restrict__ uvc,
    u16* __restrict__ xiH, u16* __restrict__ xiL,
    u16* __restrict__ phiH, u16* __restrict__ phiL)
{
  int bid = blockIdx.x, tid = threadIdx.x;
  if (bid < 64){
    __shared__ float wq[HIDN];
    __shared__ float part[256];
    int a = bid;
    wq[tid] = Wq[a*HIDN + tid];
    __syncthreads();
    int bcol = tid & 63, q = tid >> 6;
    float s = 0.f;
    for (int h = q*64; h < q*64 + 64; ++h)
      s = fmaf(wq[h], Wk[bcol*HIDN + h], s);
    part[tid] = s;
    __syncthreads();
    if (tid < 64){
      float mv = part[tid] + part[64+tid] + part[128+tid] + part[192+tid];
      u16 hh = f2bf(mv); float hf = __uint_as_float(((u32)hh)<<16);
      u16 ll = f2bf(mv - hf);
      MtH[tid*64 + a] = hh;          // Mt[c][a] = M[a][c]
      MtL[tid*64 + a] = ll;
    }
    if (tid == 0){
      float su = 0.f;
      for (int h=0; h<HIDN; ++h) su = fmaf(wq[h], bk[h], su);
      uvc[a] = su;
    }
    if (tid == 1){
      float sv = 0.f;
      for (int h=0; h<HIDN; ++h) sv = fmaf(Wk[a*HIDN + h], bq[h], sv);
      uvc[64 + a] = sv;
    }
    if (a == 0 && tid == 2){
      float c = 0.f;
      for (int h=0; h<HIDN; ++h) c = fmaf(bq[h], bk[h], c);
      uvc[128] = c;
    }
  } else {
    int t = (bid-64)*256 + tid;
    if (t < 256*128){
      int h = t >> 7, d = t & 127;
      float v = xi_w1[d*HIDN + h];
      u16 hh = f2bf(v); float hf = __uint_as_float(((u32)hh)<<16);
      u16 ll = f2bf(v - hf);
      xiH[h*128 + d] = hh; xiL[h*128 + d] = ll;
    } else {
      int t2 = t - 256*128;
      int h = t2 >> 6, d = t2 & 63;
      float v = phi_w1[d*HIDN + h];
      u16 hh = f2bf(v); float hf = __uint_as_float(((u32)hh)<<16);
      u16 ll = f2bf(v - hf);
      phiH[h*64 + d] = hh; phiL[h*64 + d] = ll;
    }
  }
}

// ---------- K-FUSED (512 threads / 8 waves): split + y-MFMA + scoring + per-unit top-k ----------
// grid 512 (1 batch/block), ~113 KB dynamic LDS. (r9-best configuration: VGPR 104, no spill)
__global__ __launch_bounds__(512) void k_fused(
    const float* __restrict__ x, const u16* __restrict__ MtH, const u16* __restrict__ MtL,
    const float* __restrict__ uvc,
    u64* __restrict__ cand, int* __restrict__ cand_n)
{
  extern __shared__ __align__(16) u16 smem[];
  u16* XH = smem;                       // [256][72]
  u16* XL = XH + 256*72;                // [256][72]
  u16* YH = XL + 256*72;                // [128][72] wave-local y bounce
  u16* YL = YH + 128*72;
  float* STS = (float*)(YL + 128*72);   // [256] s_i + c (pad -> -1e38)
  float* STT = STS + 256;               // [256] t_j   (pad -> -1e38)
  float* SUV = STT + 256;               // [129]

  int tid = threadIdx.x;
  int b = blockIdx.x;
  const float* xb = x + (size_t)b*(L_SEQ*D_IN);

  if (tid < 129) SUV[tid] = uvc[tid];

  // ---- Phase A: load + split x into LDS ----
  int ar = tid >> 1, ahf = tid & 1;
  float v[32];
  {
    const float* src = xb + (size_t)ar*D_IN + ahf*32;
    #pragma unroll
    for (int i=0;i<8;++i) *(float4*)&v[i*4] = *(const float4*)(src + i*4);
    u32 hp[16], lp[16];
    cvt8(&v[0],  &hp[0],  &lp[0]);
    cvt8(&v[8],  &hp[4],  &lp[4]);
    cvt8(&v[16], &hp[8],  &lp[8]);
    cvt8(&v[24], &hp[12], &lp[12]);
    u16* dh = XH + ar*72 + ahf*32;
    u16* dl = XL + ar*72 + ahf*32;
    #pragma unroll
    for (int i=0;i<4;++i){
      *(uint4*)(dh + i*8) = make_uint4(hp[i*4],hp[i*4+1],hp[i*4+2],hp[i*4+3]);
      *(uint4*)(dl + i*8) = make_uint4(lp[i*4],lp[i*4+1],lp[i*4+2],lp[i*4+3]);
    }
  }
  __syncthreads();   // SUV + XH/XL visible

  // ---- s_i, t_j, pad ----
  {
    float pA=0.f, pB=0.f, qA=0.f, qB=0.f, pa=0.f;
    #pragma unroll
    for (int d=0; d<16; ++d){
      float xa = v[d];
      pA = fmaf(xa, SUV[ahf*32+d], pA);
      qA = fmaf(xa, SUV[64+ahf*32+d], qA);
      pa += fabsf(xa);
    }
    #pragma unroll
    for (int d=16; d<32; ++d){
      float xa = v[d];
      pB = fmaf(xa, SUV[ahf*32+d], pB);
      qB = fmaf(xa, SUV[64+ahf*32+d], qB);
      pa += fabsf(xa);
    }
    float su = pA + pB, tv = qA + qB;
    su += __shfl_xor(su,1); tv += __shfl_xor(tv,1); pa += __shfl_xor(pa,1);
    if (ahf == 0){
      bool pad = (pa != 0.f);
      STS[ar] = pad ? (su + SUV[128]) : -1e38f;
      STT[ar] = pad ? tv : -1e38f;
    }
  }
  __syncthreads();   // STS/STT visible

  int w = tid >> 6, lane = tid & 63, lm = lane & 15, quad = lane >> 4;

  for (int half=0; half<2; ++half){
    int u = w + 8*half;       // row-unit: rows [16u, 16u+16)
    int r0 = u*16;

    // ---- y = x M for own rows via split-bf16 MFMA (C-layout -> LDS bounce) ----
    {
      const u16* ah = XH + (r0+lm)*72;
      const u16* al = XL + (r0+lm)*72;
      bf16x8 Ah0 = *(const bf16x8*)(ah + quad*8);
      bf16x8 Ah1 = *(const bf16x8*)(ah + 32 + quad*8);
      bf16x8 Al0 = *(const bf16x8*)(al + quad*8);
      bf16x8 Al1 = *(const bf16x8*)(al + 32 + quad*8);
      #pragma unroll
      for (int ct=0; ct<4; ++ct){
        const u16* mth = MtH + (ct*16+lm)*64 + quad*8;
        const u16* mtl = MtL + (ct*16+lm)*64 + quad*8;
        bf16x8 Bh0 = *(const bf16x8*)(mth);
        bf16x8 Bh1 = *(const bf16x8*)(mth + 32);
        bf16x8 Bl0 = *(const bf16x8*)(mtl);
        bf16x8 Bl1 = *(const bf16x8*)(mtl + 32);
        f32x4 a1 = {0.f,0.f,0.f,0.f}, a2 = {0.f,0.f,0.f,0.f};
        a1 = __builtin_amdgcn_mfma_f32_16x16x32_bf16(Ah0, Bh0, a1, 0,0,0);
        a2 = __builtin_amdgcn_mfma_f32_16x16x32_bf16(Ah1, Bh1, a2, 0,0,0);
        a1 = __builtin_amdgcn_mfma_f32_16x16x32_bf16(Al0, Bh0, a1, 0,0,0);
        a2 = __builtin_amdgcn_mfma_f32_16x16x32_bf16(Al1, Bh1, a2, 0,0,0);
        a1 = __builtin_amdgcn_mfma_f32_16x16x32_bf16(Ah0, Bl0, a1, 0,0,0);
        a2 = __builtin_amdgcn_mfma_f32_16x16x32_bf16(Ah1, Bl1, a2, 0,0,0);
        #pragma unroll
        for (int rg=0; rg<4; ++rg){
          float vy = a1[rg] + a2[rg];
          u16 hh = f2bf(vy); float hf = __uint_as_float(((u32)hh)<<16);
          u16 ll = f2bf(vy - hf);
          YH[(w*16 + quad*4 + rg)*72 + ct*16 + lm] = hh;   // wave-local rows, no barrier
          YL[(w*16 + quad*4 + rg)*72 + ct*16 + lm] = ll;
        }
      }
    }
    // readback y A-frags (wave-local)
    const u16* yh_ = YH + (w*16+lm)*72;
    const u16* yl_ = YL + (w*16+lm)*72;
    bf16x8 Yh0 = *(const bf16x8*)(yh_ + quad*8);
    bf16x8 Yh1 = *(const bf16x8*)(yh_ + 32 + quad*8);
    bf16x8 Yl0 = *(const bf16x8*)(yl_ + quad*8);
    bf16x8 Yl1 = *(const bf16x8*)(yl_ + 32 + quad*8);

    float sr[4];
    #pragma unroll
    for (int r=0;r<4;++r) sr[r] = STS[r0 + quad*4 + r];

    // ---- two column-halves: score 16x128, select, emit (kv[32] per lane) ----
    for (int ch=0; ch<2; ++ch){
      int j0 = ch*128;
      u32 kv[32];
      #pragma unroll
      for (int ct=0; ct<8; ++ct){
        const u16* bh = XH + (j0 + ct*16+lm)*72;
        const u16* bl = XL + (j0 + ct*16+lm)*72;
        bf16x8 Bh0 = *(const bf16x8*)(bh + quad*8);
        bf16x8 Bh1 = *(const bf16x8*)(bh + 32 + quad*8);
        bf16x8 Bl0 = *(const bf16x8*)(bl + quad*8);
        bf16x8 Bl1 = *(const bf16x8*)(bl + 32 + quad*8);
        f32x4 a1 = {0.f,0.f,0.f,0.f}, a2 = {0.f,0.f,0.f,0.f};
        a1 = __builtin_amdgcn_mfma_f32_16x16x32_bf16(Yh0, Bh0, a1, 0,0,0);
        a2 = __builtin_amdgcn_mfma_f32_16x16x32_bf16(Yh1, Bh1, a2, 0,0,0);
        a1 = __builtin_amdgcn_mfma_f32_16x16x32_bf16(Yl0, Bh0, a1, 0,0,0);
        a2 = __builtin_amdgcn_mfma_f32_16x16x32_bf16(Yl1, Bh1, a2, 0,0,0);
        a1 = __builtin_amdgcn_mfma_f32_16x16x32_bf16(Yh0, Bl0, a1, 0,0,0);
        a2 = __builtin_amdgcn_mfma_f32_16x16x32_bf16(Yh1, Bl1, a2, 0,0,0);
        float tc = STT[j0 + ct*16 + lm];
        #pragma unroll
        for (int r=0;r<4;++r)
          kv[ct*4 + r] = sortKey(a1[r] + a2[r] + sr[r] + tc);
      }

      // 16-bit-prefix threshold (top-128 of 2048), early-exit in [TOPK, CAP]
      u32 T = 0;
      for (int bit=15; bit>=0; --bit){
        u32 th2 = (T | (1u<<bit)) << 16;
        int c = 0;
        #pragma unroll
        for (int i=0;i<32;++i)
          c += (int)__popcll(__ballot(kv[i] >= th2));
        if (c >= TOPK){
          T |= (1u<<bit);
          if (c <= CAP) break;
        }
      }
      u32 thr = T << 16;
      u32 up  = (T < 0xffffu) ? ((T+1u) << 16) : 0xffffffffu;

      // two-class emission: above-bucket first (count < 128 guaranteed), then T-bucket
      u32 m1 = 0, m2 = 0;
      #pragma unroll
      for (int i=0;i<32;++i){
        bool ge = kv[i] >= thr;
        bool c1 = ge && (kv[i] >= up);
        m1 |= (c1 ? 1u : 0u) << i;
        m2 |= ((ge && !c1) ? 1u : 0u) << i;
      }
      int n1 = __popc(m1), n2 = __popc(m2);
      int p1 = n1, p2 = n2;
      #pragma unroll
      for (int off=1; off<64; off<<=1){
        int a = __shfl_up(p1, off); if (lane >= off) p1 += a;
        int c = __shfl_up(p2, off); if (lane >= off) p2 += c;
      }
      int tot1 = __shfl(p1, 63), tot2 = __shfl(p2, 63);
      int pos1 = p1 - n1;
      int pos2 = tot1 + (p2 - n2);
      int total = tot1 + tot2;
      int wt = u*2 + ch;
      size_t base = ((size_t)b*NWT + wt)*CAP;
      if (lane == 0) cand_n[b*NWT + wt] = (total < CAP) ? total : CAP;
      while (m1){
        int i = __ffs(m1) - 1; m1 &= m1 - 1;
        if (pos1 < CAP){
          int r = i & 3, ct = i >> 2;
          int flat = (r0 + quad*4 + r)*L_SEQ + (j0 + ct*16 + lm);
          cand[base + pos1] = ((u64)kv[i] << 32) | (u32)flat;
        }
        ++pos1;
      }
      while (m2){
        int i = __ffs(m2) - 1; m2 &= m2 - 1;
        if (pos2 < CAP){
          int r = i & 3, ct = i >> 2;
          int flat = (r0 + quad*4 + r)*L_SEQ + (j0 + ct*16 + lm);
          cand[base + pos2] = ((u64)kv[i] << 32) | (u32)flat;
        }
        ++pos2;
      }
    }
  }
}

// ---------- FALLBACK K1: split x; st; y via MFMA ----------
__global__ __launch_bounds__(256) void k_pre(
    const float* __restrict__ x, const u16* __restrict__ MtH, const u16* __restrict__ MtL,
    const float* __restrict__ uvc,
    u16* __restrict__ xh, u16* __restrict__ xl,
    u16* __restrict__ yh, u16* __restrict__ yl,
    float* __restrict__ st)
{
  __shared__ __align__(16) u16 sh[64][72];
  __shared__ __align__(16) u16 sl[64][72];
  __shared__ float sUV[132];
  int tid = threadIdx.x;
  int g0 = blockIdx.x * 64;
  int b  = g0 >> 8, l0 = g0 & 255;
  int r = tid >> 2, q = tid & 3;

  if (tid < 129) sUV[tid] = uvc[tid];

  float v[16];
  {
    const float* xr = x + (size_t)(g0 + r)*D_IN + q*16;
    #pragma unroll
    for (int i=0;i<4;++i) *(float4*)&v[i*4] = *(const float4*)(xr + i*4);
  }
  {
    u32 hpA[4],lpA[4],hpB[4],lpB[4];
    cvt8(&v[0], hpA, lpA); cvt8(&v[8], hpB, lpB);
    size_t xo = (size_t)(g0 + r)*D_IN + q*16;
    *(uint4*)(xh + xo)     = make_uint4(hpA[0],hpA[1],hpA[2],hpA[3]);
    *(uint4*)(xh + xo + 8) = make_uint4(hpB[0],hpB[1],hpB[2],hpB[3]);
    *(uint4*)(xl + xo)     = make_uint4(lpA[0],lpA[1],lpA[2],lpA[3]);
    *(uint4*)(xl + xo + 8) = make_uint4(lpB[0],lpB[1],lpB[2],lpB[3]);
    *(uint4*)&sh[r][q*16]   = make_uint4(hpA[0],hpA[1],hpA[2],hpA[3]);
    *(uint4*)&sh[r][q*16+8] = make_uint4(hpB[0],hpB[1],hpB[2],hpB[3]);
    *(uint4*)&sl[r][q*16]   = make_uint4(lpA[0],lpA[1],lpA[2],lpA[3]);
    *(uint4*)&sl[r][q*16+8] = make_uint4(lpB[0],lpB[1],lpB[2],lpB[3]);
  }
  __syncthreads();

  {
    float su=0.f, tv=0.f, pa=0.f;
    #pragma unroll
    for (int d=0; d<16; ++d){
      float xa = v[d];
      su = fmaf(xa, sUV[q*16+d], su);
      tv = fmaf(xa, sUV[64+q*16+d], tv);
      pa += fabsf(xa);
    }
    su += __shfl_xor(su,1); su += __shfl_xor(su,2);
    tv += __shfl_xor(tv,1); tv += __shfl_xor(tv,2);
    pa += __shfl_xor(pa,1); pa += __shfl_xor(pa,2);
    if (q == 0){
      bool pad = (pa != 0.f);
      st[(size_t)b*L_SEQ + l0 + r]          = pad ? (su + sUV[128]) : -1e38f;
      st[(size_t)(B_TOT+b)*L_SEQ + l0 + r]  = pad ? tv : -1e38f;
    }
  }

  int w = tid >> 6, lane = tid & 63, lm = lane & 15, quad = lane >> 4;
  bf16x8 Ah0 = *(const bf16x8*)&sh[w*16+lm][quad*8];
  bf16x8 Ah1 = *(const bf16x8*)&sh[w*16+lm][32 + quad*8];
  bf16x8 Al0 = *(const bf16x8*)&sl[w*16+lm][quad*8];
  bf16x8 Al1 = *(const bf16x8*)&sl[w*16+lm][32 + quad*8];
  #pragma unroll
  for (int ct=0; ct<4; ++ct){
    const u16* mth = MtH + (ct*16+lm)*64 + quad*8;
    const u16* mtl = MtL + (ct*16+lm)*64 + quad*8;
    bf16x8 Bh0 = *(const bf16x8*)(mth);
    bf16x8 Bh1 = *(const bf16x8*)(mth + 32);
    bf16x8 Bl0 = *(const bf16x8*)(mtl);
    bf16x8 Bl1 = *(const bf16x8*)(mtl + 32);
    f32x4 a1 = {0.f,0.f,0.f,0.f}, a2 = {0.f,0.f,0.f,0.f};
    a1 = __builtin_amdgcn_mfma_f32_16x16x32_bf16(Ah0, Bh0, a1, 0,0,0);
    a2 = __builtin_amdgcn_mfma_f32_16x16x32_bf16(Ah1, Bh1, a2, 0,0,0);
    a1 = __builtin_amdgcn_mfma_f32_16x16x32_bf16(Al0, Bh0, a1, 0,0,0);
    a2 = __builtin_amdgcn_mfma_f32_16x16x32_bf16(Al1, Bh1, a2, 0,0,0);
    a1 = __builtin_amdgcn_mfma_f32_16x16x32_bf16(Ah0, Bl0, a1, 0,0,0);
    a2 = __builtin_amdgcn_mfma_f32_16x16x32_bf16(Ah1, Bl1, a2, 0,0,0);
    #pragma unroll
    for (int rg=0; rg<4; ++rg){
      float vy = a1[rg] + a2[rg];
      u16 hh = f2bf(vy); float hf = __uint_as_float(((u32)hh)<<16);
      u16 ll = f2bf(vy - hf);
      sh[w*16 + quad*4 + rg][ct*16 + lm] = hh;
      sl[w*16 + quad*4 + rg][ct*16 + lm] = ll;
    }
  }
  {
    size_t yo = (size_t)(g0 + r)*D_IN + q*16;
    *(uint4*)(yh + yo)     = *(uint4*)&sh[r][q*16];
    *(uint4*)(yh + yo + 8) = *(uint4*)&sh[r][q*16+8];
    *(uint4*)(yl + yo)     = *(uint4*)&sl[r][q*16];
    *(uint4*)(yl + yo + 8) = *(uint4*)&sl[r][q*16+8];
  }
}

// ---------- FALLBACK K2: k_score ----------
__global__ __launch_bounds__(256) void k_score(
    const u16* __restrict__ xh, const u16* __restrict__ xl,
    const u16* __restrict__ yh, const u16* __restrict__ yl,
    const float* __restrict__ st,
    u64* __restrict__ cand, int* __restrict__ cand_n)
{
  int tid = threadIdx.x;
  int lin = blockIdx.x;
  int b    = ((lin >> 6) << 3) | (lin & 7);
  int tile = (lin >> 3) & 7;
  int cb = tile & 1, rb = tile >> 1;
  int r0 = rb*64, j0 = cb*128;
  int w = tid >> 6, lane = tid & 63, lm = lane & 15, quad = lane >> 4;

  size_t rowA = ((size_t)b*L_SEQ + r0 + w*16 + lm)*D_IN;
  bf16x8 A_h0 = *(const bf16x8*)(yh + rowA + quad*8);
  bf16x8 A_h1 = *(const bf16x8*)(yh + rowA + 32 + quad*8);
  bf16x8 A_l0 = *(const bf16x8*)(yl + rowA + quad*8);
  bf16x8 A_l1 = *(const bf16x8*)(yl + rowA + 32 + quad*8);

  float4 s4 = *(const float4*)(st + (size_t)b*L_SEQ + r0 + w*16 + quad*4);
  float sr[4] = {s4.x, s4.y, s4.z, s4.w};
  float tc[8];
  #pragma unroll
  for (int ct=0;ct<8;++ct)
    tc[ct] = st[(size_t)(B_TOT + b)*L_SEQ + j0 + ct*16 + lm];

  u32 kv[32];
  #pragma unroll
  for (int ct=0; ct<8; ++ct){
    size_t rowB = ((size_t)b*L_SEQ + j0 + ct*16 + lm)*D_IN;
    bf16x8 B_h0 = *(const bf16x8*)(xh + rowB + quad*8);
    bf16x8 B_h1 = *(const bf16x8*)(xh + rowB + 32 + quad*8);
    bf16x8 B_l0 = *(const bf16x8*)(xl + rowB + quad*8);
    bf16x8 B_l1 = *(const bf16x8*)(xl + rowB + 32 + quad*8);
    f32x4 a1 = {0.f,0.f,0.f,0.f}, a2 = {0.f,0.f,0.f,0.f};
    a1 = __builtin_amdgcn_mfma_f32_16x16x32_bf16(A_h0, B_h0, a1, 0,0,0);
    a2 = __builtin_amdgcn_mfma_f32_16x16x32_bf16(A_h1, B_h1, a2, 0,0,0);
    a1 = __builtin_amdgcn_mfma_f32_16x16x32_bf16(A_l0, B_h0, a1, 0,0,0);
    a2 = __builtin_amdgcn_mfma_f32_16x16x32_bf16(A_l1, B_h1, a2, 0,0,0);
    a1 = __builtin_amdgcn_mfma_f32_16x16x32_bf16(A_h0, B_l0, a1, 0,0,0);
    a2 = __builtin_amdgcn_mfma_f32_16x16x32_bf16(A_h1, B_l1, a2, 0,0,0);
    #pragma unroll
    for (int r=0;r<4;++r)
      kv[ct*4 + r] = sortKey(a1[r] + a2[r] + sr[r] + tc[ct]);
  }

  u32 T = 0;
  for (int bit=15; bit>=0; --bit){
    u32 th2 = (T | (1u<<bit)) << 16;
    int c = 0;
    #pragma unroll
    for (int i=0;i<32;++i)
      c += (int)__popcll(__ballot(kv[i] >= th2));
    if (c >= TOPK){
      T |= (1u<<bit);
      if (c <= CAP) break;
    }
  }
  u32 thr = T << 16;

  u32 hm = 0;
  #pragma unroll
  for (int i=0;i<32;++i) hm |= (kv[i] >= thr ? 1u : 0u) << i;
  int myc = __popc(hm);
  int pre = myc;
  #pragma unroll
  for (int off=1; off<64; off<<=1){
    int n = __shfl_up(pre, off);
    if (lane >= off) pre += n;
  }
  int total = __shfl(pre, 63);
  int pos = pre - myc;
  int wt = tile*4 + w;
  size_t base = ((size_t)b*NWT + wt)*CAP;
  if (lane == 0) cand_n[b*NWT + wt] = (total < CAP) ? total : CAP;
  while (hm){
    int i = __ffs(hm) - 1; hm &= hm - 1;
    if (pos < CAP){
      int r = i & 3, ct = i >> 2;
      int flat = (r0 + w*16 + quad*4 + r)*L_SEQ + (j0 + ct*16 + lm);
      cand[base + pos] = ((u64)kv[i] << 32) | (u32)flat;
    }
    ++pos;
  }
}

// ---------- K3: two-stage ballot merge -> exact top-128 + softmax ----------
__global__ __launch_bounds__(256) void k_merge(
    const u64* __restrict__ cand, const int* __restrict__ cand_n,
    int* __restrict__ selidx, float* __restrict__ selw)
{
  const int SL   = NWT/4;           // 8 slots per wave
  const int NSW  = SL*CAP/64;       // 20 keys per lane
  const int WCAP = 192;
  __shared__ u64 wbuf[4][WCAP];
  __shared__ int wcnt[4];
  __shared__ int scnt[NWT];
  __shared__ int cm, eqc;
  __shared__ int eqi[256];
  __shared__ float sv[TOPK]; __shared__ int si[TOPK];
  __shared__ float fred[8];
  int b = blockIdx.x, tid = threadIdx.x;
  int w = tid >> 6, lane = tid & 63;
  if (tid < NWT) scnt[tid] = cand_n[b*NWT + tid];
  if (tid == 0){ cm = 0; eqc = 0; }
  __syncthreads();

  u32 key[NSW]; int idx[NSW];
  size_t bb = (size_t)b*NWT*CAP + (size_t)(w*SL)*CAP;
  #pragma unroll
  for (int s=0;s<NSW;++s){
    int e = lane + 64*s;
    int slot = e / CAP, p = e - slot*CAP;
    bool ok = p < scnt[w*SL + slot];
    u64 v = ok ? cand[bb + e] : 0ull;
    key[s] = (u32)(v >> 32);
    idx[s] = ok ? (int)(u32)v : 0x7fffffff;
  }

  u32 T = 0;
  for (int bit=31; bit>=0; --bit){
    u32 c2 = T | (1u<<bit);
    int c = 0;
    #pragma unroll
    for (int s=0;s<NSW;++s) c += (int)__popcll(__ballot(key[s] >= c2));
    if (c >= TOPK){
      T = c2;
      if (c <= WCAP) break;
    }
  }
  {
    int myc = 0;
    #pragma unroll
    for (int s=0;s<NSW;++s) myc += (key[s] >= T) ? 1 : 0;
    int pre = myc;
    #pragma unroll
    for (int off=1; off<64; off<<=1){
      int n = __shfl_up(pre, off);
      if (lane >= off) pre += n;
    }
    int total = __shfl(pre, 63);
    int pos = pre - myc;
    if (lane == 0) wcnt[w] = (total < WCAP) ? total : WCAP;
    #pragma unroll
    for (int s=0;s<NSW;++s){
      if (key[s] >= T){
        if (pos < WCAP) wbuf[w][pos] = ((u64)key[s] << 32) | (u32)idx[s];
        ++pos;
      }
    }
  }
  __syncthreads();

  if (w == 0){
    const int NS2 = 4*WCAP/64;   // 12
    u32 k2[NS2]; int i2[NS2];
    #pragma unroll
    for (int s=0;s<NS2;++s){
      int e = lane + 64*s;
      int slot = e / WCAP, p = e - slot*WCAP;
      bool ok = p < wcnt[slot];
      u64 v = ok ? wbuf[slot][p] : 0ull;
      k2[s] = (u32)(v >> 32);
      i2[s] = ok ? (int)(u32)v : 0x7fffffff;
    }
    u32 T2 = 0;
    for (int bit=31; bit>=0; --bit){
      u32 c2 = T2 | (1u<<bit);
      int c = 0;
      #pragma unroll
      for (int s=0;s<NS2;++s) c += (int)__popcll(__ballot(k2[s] >= c2));
      if (c >= TOPK) T2 = c2;
    }
    int m = 0;
    #pragma unroll
    for (int s=0;s<NS2;++s) m += (int)__popcll(__ballot(k2[s] > T2));
    #pragma unroll
    for (int s=0;s<NS2;++s){
      if (k2[s] > T2){
        int p = atomicAdd(&cm, 1);
        sv[p] = unKey(k2[s]) * 0.0625f; si[p] = i2[s];
      } else if (k2[s] == T2 && i2[s] != 0x7fffffff){
        int q = atomicAdd(&eqc, 1);
        if (q < 256) eqi[q] = i2[s];
      }
    }
    if (lane == 0){
      int need = TOPK - m;
      int n = eqc < 256 ? eqc : 256;
      float tv = unKey(T2) * 0.0625f;
      for (int s2=0; s2<need; ++s2){
        int bi = s2;
        for (int j=s2+1;j<n;++j) if (eqi[j] < eqi[bi]) bi = j;
        int t2 = eqi[s2]; eqi[s2] = eqi[bi]; eqi[bi] = t2;
        sv[m+s2] = tv; si[m+s2] = eqi[s2];
      }
    }
  }
  __syncthreads();

  float v = (tid < TOPK) ? sv[tid] : -3.4e38f;
  float mx = v;
  #pragma unroll
  for (int off=1; off<64; off<<=1) mx = fmaxf(mx, __shfl_xor(mx, off));
  if ((tid&63)==0) fred[tid>>6] = mx;
  __syncthreads();
  mx = fmaxf(fred[0], fred[1]);
  float e = (tid < TOPK) ? expf(v - mx) : 0.f;
  float s = e;
  #pragma unroll
  for (int off=1; off<64; off<<=1) s += __shfl_xor(s, off);
  if ((tid&63)==0) fred[4 + (tid>>6)] = s;
  __syncthreads();
  s = fred[4] + fred[5];
  if (tid < TOPK){
    selw[(size_t)b*TOPK + tid]   = e / s;
    selidx[(size_t)b*TOPK + tid] = si[tid];
  }
}

// ---------- K4: gather + split-bf16 MFMA MLP1 + pooling + rho (512 threads / 8 waves) ----------
__global__ __launch_bounds__(512, 4) void k_mlp(
    const float* __restrict__ x, const int* __restrict__ selidx, const float* __restrict__ selw,
    const u16* __restrict__ xiH, const u16* __restrict__ xiL,
    const u16* __restrict__ phiH, const u16* __restrict__ phiL,
    const float* __restrict__ phi_b1, const float* __restrict__ phi_w2, const float* __restrict__ phi_b2,
    const float* __restrict__ xi_b1,  const float* __restrict__ xi_w2,  const float* __restrict__ xi_b2,
    const float* __restrict__ rho_w1, const float* __restrict__ rho_b1,
    const float* __restrict__ rho_w2, const float* __restrict__ rho_b2,
    float* __restrict__ out)
{
  __shared__ __align__(16) u16 AFh[8][4][64][8];
  __shared__ __align__(16) u16 AFl[8][4][64][8];
  __shared__ int   sidx[TOPK];
  __shared__ float swp[TOPK], swd[TOPK];
  __shared__ float gpL[256], gsL[256];
  __shared__ float pooled[256], t1[256];
  __shared__ float wsums[2];
  int b = blockIdx.x, tid = threadIdx.x;

  if (tid < TOPK){
    int fl = selidx[(size_t)b*TOPK + tid];
    sidx[tid] = fl;
    float wv = selw[(size_t)b*TOPK + tid];
    bool dg = ((fl>>8) == (fl&255));
    swp[tid] = dg ? 0.f : wv;
    swd[tid] = dg ? wv  : 0.f;
  }
  __syncthreads();
  if (tid == 0){
    float a=0.f, c2=0.f;
    for (int k=0;k<TOPK;++k){ a+=swp[k]; c2+=swd[k]; }
    wsums[0]=a; wsums[1]=c2;
  }
  // gather: 512 threads, each does 4 chunks (same values/layout as the 256-thread version)
  {
    int m = tid >> 2, hf = (tid >> 1) & 1, gsel = tid & 1;
    int fl = sidx[m];
    int rc = hf ? (fl & 255) : (fl >> 8);
    const float* src = x + ((size_t)b*L_SEQ + rc)*D_IN;
    int kt = m >> 4, l16 = m & 15;
    #pragma unroll
    for (int gg=0; gg<4; ++gg){
      int g = gsel*4 + gg;
      int d0 = hf*64 + g*8;
      int c = d0 >> 5, q = (d0 >> 3) & 3;
      float v[8];
      *(float4*)&v[0] = *(const float4*)(src + (d0 & 63));
      *(float4*)&v[4] = *(const float4*)(src + (d0 & 63) + 4);
      u32 hp[4], lp[4];
      cvt8(v, hp, lp);
      *(uint4*)&AFh[kt][c][l16 + 16*q][0] = make_uint4(hp[0],hp[1],hp[2],hp[3]);
      *(uint4*)&AFl[kt][c][l16 + 16*q][0] = make_uint4(lp[0],lp[1],lp[2],lp[3]);
    }
  }
  __syncthreads();

  int w = tid >> 6, lane = tid & 63;
  int lm = lane & 15, quad = lane >> 4;

  #pragma unroll
  for (int hi2=0; hi2<2; ++hi2){
    int ht = w + 8*hi2;
    int h  = ht*16 + lm;
    bf16x8 BXh[4], BXl[4], BPh[2], BPl[2];
    #pragma unroll
    for (int c=0;c<4;++c){
      BXh[c] = *(const bf16x8*)(xiH + h*128 + c*32 + quad*8);
      BXl[c] = *(const bf16x8*)(xiL + h*128 + c*32 + quad*8);
    }
    #pragma unroll
    for (int c=0;c<2;++c){
      BPh[c] = *(const bf16x8*)(phiH + h*64 + c*32 + quad*8);
      BPl[c] = *(const bf16x8*)(phiL + h*64 + c*32 + quad*8);
    }
    float bxi = xi_b1[h], bph = phi_b1[h];
    float gp = 0.f, gs = 0.f;
    for (int kt=0; kt<8; ++kt){
      bf16x8 Ah_[4], Al_[4];
      #pragma unroll
      for (int c=0;c<4;++c){
        Ah_[c] = *(const bf16x8*)&AFh[kt][c][lane][0];
        Al_[c] = *(const bf16x8*)&AFl[kt][c][lane][0];
      }
      f32x4 cx = {0.f,0.f,0.f,0.f}, cp = {0.f,0.f,0.f,0.f};
      #pragma unroll
      for (int c=0;c<4;++c){
        cx = __builtin_amdgcn_mfma_f32_16x16x32_bf16(Ah_[c], BXh[c], cx, 0,0,0);
        cx = __builtin_amdgcn_mfma_f32_16x16x32_bf16(Al_[c], BXh[c], cx, 0,0,0);
        cx = __builtin_amdgcn_mfma_f32_16x16x32_bf16(Ah_[c], BXl[c], cx, 0,0,0);
      }
      #pragma unroll
      for (int c=0;c<2;++c){
        cp = __builtin_amdgcn_mfma_f32_16x16x32_bf16(Ah_[c], BPh[c], cp, 0,0,0);
        cp = __builtin_amdgcn_mfma_f32_16x16x32_bf16(Al_[c], BPh[c], cp, 0,0,0);
        cp = __builtin_amdgcn_mfma_f32_16x16x32_bf16(Ah_[c], BPl[c], cp, 0,0,0);
      }
      #pragma unroll
      for (int r=0;r<4;++r){
        int kk = kt*16 + quad*4 + r;
        gp = fmaf(swp[kk], fmaxf(cx[r] + bxi, 0.f), gp);
        gs = fmaf(swd[kk], fmaxf(cp[r] + bph, 0.f), gs);
      }
    }
    gp += __shfl_xor(gp, 16); gp += __shfl_xor(gp, 32);
    gs += __shfl_xor(gs, 16); gs += __shfl_xor(gs, 32);
    if (quad == 0){ gpL[h] = gp; gsL[h] = gs; }
  }
  __syncthreads();

  if (tid < 256){
    int h = tid;
    float wsp = wsums[0], wss = wsums[1];
    float po = wsp*xi_b2[h] + wss*phi_b2[h];
    for (int d=0; d<256; ++d){
      po = fmaf(gpL[d], xi_w2[d*HIDN + h], po);
      po = fmaf(gsL[d], phi_w2[d*HIDN + h], po);
    }
    pooled[h] = po;
  }
  __syncthreads();
  if (tid < 256){
    int h = tid;
    float a = rho_b1[h];
    for (int d=0; d<256; ++d) a = fmaf(pooled[d], rho_w1[d*HIDN + h], a);
    t1[h] = fmaxf(a, 0.f);
  }
  __syncthreads();
  if (tid < 128){
    int h = tid;
    float o = rho_b2[h];
    for (int d=0; d<256; ++d) o = fmaf(t1[d], rho_w2[d*128 + h], o);
    out[(size_t)b*128 + h] = o;
  }
}

// ---------- host ----------
extern "C" void kernel_launch(void* const* d_in, const int* in_sizes, int n_in,
                              void* d_out, int out_size, void* d_ws, size_t ws_size,
                              hipStream_t stream)
{
  (void)in_sizes; (void)n_in; (void)out_size; (void)ws_size;
  const float* x      = (const float*)d_in[0];
  const float* Wq     = (const float*)d_in[1];
  const float* bq     = (const float*)d_in[2];
  const float* Wk     = (const float*)d_in[3];
  const float* bk     = (const float*)d_in[4];
  const float* phi_w1 = (const float*)d_in[5];
  const float* phi_b1 = (const float*)d_in[6];
  const float* phi_w2 = (const float*)d_in[7];
  const float* phi_b2 = (const float*)d_in[8];
  const float* xi_w1  = (const float*)d_in[9];
  const float* xi_b1  = (const float*)d_in[10];
  const float* xi_w2  = (const float*)d_in[11];
  const float* xi_b2  = (const float*)d_in[12];
  const float* rho_w1 = (const float*)d_in[13];
  const float* rho_b1 = (const float*)d_in[14];
  const float* rho_w2 = (const float*)d_in[15];
  const float* rho_b2 = (const float*)d_in[16];
  float* out = (float*)d_out;

  const size_t NX = (size_t)B_TOT*L_SEQ*D_IN;      // 8,388,608
  float* uvc    = (float*)d_ws;                    // 256
  float* st     = uvc + 256;                       // 2*512*256
  float* selw   = st + (size_t)2*B_TOT*L_SEQ;      // 512*128
  int*   selidx = (int*)(selw + (size_t)B_TOT*TOPK);
  int*   cand_n = selidx + (size_t)B_TOT*TOPK;     // 512*32
  u64*   cand   = (u64*)(cand_n + (size_t)B_TOT*NWT);
  u16*   MtH    = (u16*)(cand + (size_t)B_TOT*NWT*CAP);
  u16*   MtL    = MtH + 64*64;
  u16*   xiH    = MtL + 64*64;
  u16*   xiL    = xiH + 256*128;
  u16*   phiH   = xiL + 256*128;
  u16*   phiL   = phiH + 256*64;
  u16*   xh     = phiL + 256*64;
  u16*   xl     = xh + NX;
  u16*   yh     = xl + NX;
  u16*   yl     = yh + NX;

  // deterministic per-device check (same result every call -> graph-safe)
  hipError_t aerr = hipFuncSetAttribute((const void*)k_fused,
                      hipFuncAttributeMaxDynamicSharedMemorySize, FLDS);

  k_wprep<<<dim3(256),  dim3(256), 0, stream>>>(Wq, bq, Wk, bk, xi_w1, phi_w1,
                                                MtH, MtL, uvc, xiH, xiL, phiH, phiL);
  if (aerr == hipSuccess){
    k_fused<<<dim3(B_TOT), dim3(512), FLDS, stream>>>(x, MtH, MtL, uvc, cand, cand_n);
  } else {
    k_pre  <<<dim3(2048), dim3(256), 0, stream>>>(x, MtH, MtL, uvc, xh, xl, yh, yl, st);
    k_score<<<dim3(4096), dim3(256), 0, stream>>>(xh, xl, yh, yl, st, cand, cand_n);
  }
  k_merge<<<dim3(B_TOT), dim3(256), 0, stream>>>(cand, cand_n, selidx, selw);
  k_mlp  <<<dim3(B_TOT), dim3(512), 0, stream>>>(x, selidx, selw,
            xiH, xiL, phiH, phiL,
            phi_b1, phi_w2, phi_b2,
            xi_b1, xi_w2, xi_b2,
            rho_w1, rho_b1, rho_w2, rho_b2, out);
}

// Round 14
// 272.863 us; speedup vs baseline: 1.1896x; 1.0647x over previous
//
#include <hip/hip_runtime.h>

typedef unsigned short u16;
typedef unsigned int   u32;
typedef unsigned char  u8;
typedef unsigned long long u64;

#define B_TOT 512
#define L_SEQ 256
#define D_IN  64
#define HIDN  256
#define TOPK  128
#define CAP   160              // candidate cap per unit
#define NWT   32               // units per batch
#define FLDS  113280           // fused dynamic LDS bytes

typedef float  f32x4  __attribute__((ext_vector_type(4)));
typedef __bf16 bf16x8 __attribute__((ext_vector_type(8)));

// ---------- helpers ----------
__device__ __forceinline__ u16 f2bf(float f){
  u32 u = __float_as_uint(f);
  u32 r = u + 0x7fffu + ((u>>16)&1u);   // RNE
  return (u16)(r>>16);
}
__device__ __forceinline__ u32 sortKey(float f){
  u32 b = __float_as_uint(f);
  return (b & 0x80000000u) ? ~b : (b | 0x80000000u);
}
__device__ __forceinline__ float unKey(u32 u){
  u32 b = (u & 0x80000000u) ? (u & 0x7fffffffu) : ~u;
  return __uint_as_float(b);
}
__device__ __forceinline__ void cvt8(const float* v, u32* hp, u32* lp){
  #pragma unroll
  for (int i=0;i<4;++i){
    float v0 = v[2*i], v1 = v[2*i+1];
    u16 h0 = f2bf(v0); float h0f = __uint_as_float(((u32)h0)<<16); u16 l0 = f2bf(v0 - h0f);
    u16 h1 = f2bf(v1); float h1f = __uint_as_float(((u32)h1)<<16); u16 l1 = f2bf(v1 - h1f);
    hp[i] = (u32)h0 | ((u32)h1<<16);
    lp[i] = (u32)l0 | ((u32)l1<<16);
  }
}

// ---------- K0: fused weight prep (uvc via wave reductions, no serial tails) ----------
__global__ __launch_bounds__(256) void k_wprep(
    const float* __restrict__ Wq, const float* __restrict__ bq,
    const float* __restrict__ Wk, const float* __restrict__ bk,
    const float* __restrict__ xi_w1, const float* __restrict__ phi_w1,
    u16* __restrict__ MtH, u16* __restrict__ MtL, float* __restrict__ uvc,
    u16* __restrict__ xiH, u16* __restrict__ xiL,
    u16* __restrict__ phiH, u16* __restrict__ phiL)
{
  int bid = blockIdx.x, tid = threadIdx.x;
  if (bid < 64){
    __shared__ float wq[HIDN];
    __shared__ float part[256];
    int a = bid;
    wq[tid] = Wq[a*HIDN + tid];
    __syncthreads();
    int bcol = tid & 63, q = tid >> 6;
    float s = 0.f;
    for (int h = q*64; h < q*64 + 64; ++h)
      s = fmaf(wq[h], Wk[bcol*HIDN + h], s);
    part[tid] = s;
    __syncthreads();
    if (tid < 64){
      float mv = part[tid] + part[64+tid] + part[128+tid] + part[192+tid];
      u16 hh = f2bf(mv); float hf = __uint_as_float(((u32)hh)<<16);
      u16 ll = f2bf(mv - hf);
      MtH[tid*64 + a] = hh;          // Mt[c][a] = M[a][c]
      MtL[tid*64 + a] = ll;
    }
    // uvc via per-wave shuffle reductions (4 elems/lane)
    int wv = tid >> 6, ln = tid & 63;
    if (wv == 0){
      float s2 = 0.f;
      #pragma unroll
      for (int i=0;i<4;++i){ int h = ln*4+i; s2 = fmaf(wq[h], bk[h], s2); }
      #pragma unroll
      for (int off=1; off<64; off<<=1) s2 += __shfl_xor(s2, off);
      if (ln == 0) uvc[a] = s2;
    } else if (wv == 1){
      float s2 = 0.f;
      #pragma unroll
      for (int i=0;i<4;++i){ int h = ln*4+i; s2 = fmaf(Wk[a*HIDN + h], bq[h], s2); }
      #pragma unroll
      for (int off=1; off<64; off<<=1) s2 += __shfl_xor(s2, off);
      if (ln == 0) uvc[64 + a] = s2;
    } else if (wv == 2 && a == 0){
      float s2 = 0.f;
      #pragma unroll
      for (int i=0;i<4;++i){ int h = ln*4+i; s2 = fmaf(bq[h], bk[h], s2); }
      #pragma unroll
      for (int off=1; off<64; off<<=1) s2 += __shfl_xor(s2, off);
      if (ln == 0) uvc[128] = s2;
    }
  } else {
    int t = (bid-64)*256 + tid;
    if (t < 256*128){
      int h = t >> 7, d = t & 127;
      float v = xi_w1[d*HIDN + h];
      u16 hh = f2bf(v); float hf = __uint_as_float(((u32)hh)<<16);
      u16 ll = f2bf(v - hf);
      xiH[h*128 + d] = hh; xiL[h*128 + d] = ll;
    } else {
      int t2 = t - 256*128;
      int h = t2 >> 6, d = t2 & 63;
      float v = phi_w1[d*HIDN + h];
      u16 hh = f2bf(v); float hf = __uint_as_float(((u32)hh)<<16);
      u16 ll = f2bf(v - hf);
      phiH[h*64 + d] = hh; phiL[h*64 + d] = ll;
    }
  }
}

// ---------- K-FUSED (512 threads / 8 waves): split + y-MFMA + scoring + per-unit top-k ----------
// grid 512 (1 batch/block), ~113 KB dynamic LDS. (r9/r13-best configuration: VGPR 104, no spill)
__global__ __launch_bounds__(512) void k_fused(
    const float* __restrict__ x, const u16* __restrict__ MtH, const u16* __restrict__ MtL,
    const float* __restrict__ uvc,
    u64* __restrict__ cand, int* __restrict__ cand_n)
{
  extern __shared__ __align__(16) u16 smem[];
  u16* XH = smem;                       // [256][72]
  u16* XL = XH + 256*72;                // [256][72]
  u16* YH = XL + 256*72;                // [128][72] wave-local y bounce
  u16* YL = YH + 128*72;
  float* STS = (float*)(YL + 128*72);   // [256] s_i + c (pad -> -1e38)
  float* STT = STS + 256;               // [256] t_j   (pad -> -1e38)
  float* SUV = STT + 256;               // [129]

  int tid = threadIdx.x;
  int b = blockIdx.x;
  const float* xb = x + (size_t)b*(L_SEQ*D_IN);

  if (tid < 129) SUV[tid] = uvc[tid];

  // ---- Phase A: load + split x into LDS ----
  int ar = tid >> 1, ahf = tid & 1;
  float v[32];
  {
    const float* src = xb + (size_t)ar*D_IN + ahf*32;
    #pragma unroll
    for (int i=0;i<8;++i) *(float4*)&v[i*4] = *(const float4*)(src + i*4);
    u32 hp[16], lp[16];
    cvt8(&v[0],  &hp[0],  &lp[0]);
    cvt8(&v[8],  &hp[4],  &lp[4]);
    cvt8(&v[16], &hp[8],  &lp[8]);
    cvt8(&v[24], &hp[12], &lp[12]);
    u16* dh = XH + ar*72 + ahf*32;
    u16* dl = XL + ar*72 + ahf*32;
    #pragma unroll
    for (int i=0;i<4;++i){
      *(uint4*)(dh + i*8) = make_uint4(hp[i*4],hp[i*4+1],hp[i*4+2],hp[i*4+3]);
      *(uint4*)(dl + i*8) = make_uint4(lp[i*4],lp[i*4+1],lp[i*4+2],lp[i*4+3]);
    }
  }
  __syncthreads();   // SUV + XH/XL visible

  // ---- s_i, t_j, pad ----
  {
    float pA=0.f, pB=0.f, qA=0.f, qB=0.f, pa=0.f;
    #pragma unroll
    for (int d=0; d<16; ++d){
      float xa = v[d];
      pA = fmaf(xa, SUV[ahf*32+d], pA);
      qA = fmaf(xa, SUV[64+ahf*32+d], qA);
      pa += fabsf(xa);
    }
    #pragma unroll
    for (int d=16; d<32; ++d){
      float xa = v[d];
      pB = fmaf(xa, SUV[ahf*32+d], pB);
      qB = fmaf(xa, SUV[64+ahf*32+d], qB);
      pa += fabsf(xa);
    }
    float su = pA + pB, tv = qA + qB;
    su += __shfl_xor(su,1); tv += __shfl_xor(tv,1); pa += __shfl_xor(pa,1);
    if (ahf == 0){
      bool pad = (pa != 0.f);
      STS[ar] = pad ? (su + SUV[128]) : -1e38f;
      STT[ar] = pad ? tv : -1e38f;
    }
  }
  __syncthreads();   // STS/STT visible

  int w = tid >> 6, lane = tid & 63, lm = lane & 15, quad = lane >> 4;

  for (int half=0; half<2; ++half){
    int u = w + 8*half;       // row-unit: rows [16u, 16u+16)
    int r0 = u*16;

    // ---- y = x M for own rows via split-bf16 MFMA (C-layout -> LDS bounce) ----
    {
      const u16* ah = XH + (r0+lm)*72;
      const u16* al = XL + (r0+lm)*72;
      bf16x8 Ah0 = *(const bf16x8*)(ah + quad*8);
      bf16x8 Ah1 = *(const bf16x8*)(ah + 32 + quad*8);
      bf16x8 Al0 = *(const bf16x8*)(al + quad*8);
      bf16x8 Al1 = *(const bf16x8*)(al + 32 + quad*8);
      #pragma unroll
      for (int ct=0; ct<4; ++ct){
        const u16* mth = MtH + (ct*16+lm)*64 + quad*8;
        const u16* mtl = MtL + (ct*16+lm)*64 + quad*8;
        bf16x8 Bh0 = *(const bf16x8*)(mth);
        bf16x8 Bh1 = *(const bf16x8*)(mth + 32);
        bf16x8 Bl0 = *(const bf16x8*)(mtl);
        bf16x8 Bl1 = *(const bf16x8*)(mtl + 32);
        f32x4 a1 = {0.f,0.f,0.f,0.f}, a2 = {0.f,0.f,0.f,0.f};
        a1 = __builtin_amdgcn_mfma_f32_16x16x32_bf16(Ah0, Bh0, a1, 0,0,0);
        a2 = __builtin_amdgcn_mfma_f32_16x16x32_bf16(Ah1, Bh1, a2, 0,0,0);
        a1 = __builtin_amdgcn_mfma_f32_16x16x32_bf16(Al0, Bh0, a1, 0,0,0);
        a2 = __builtin_amdgcn_mfma_f32_16x16x32_bf16(Al1, Bh1, a2, 0,0,0);
        a1 = __builtin_amdgcn_mfma_f32_16x16x32_bf16(Ah0, Bl0, a1, 0,0,0);
        a2 = __builtin_amdgcn_mfma_f32_16x16x32_bf16(Ah1, Bl1, a2, 0,0,0);
        #pragma unroll
        for (int rg=0; rg<4; ++rg){
          float vy = a1[rg] + a2[rg];
          u16 hh = f2bf(vy); float hf = __uint_as_float(((u32)hh)<<16);
          u16 ll = f2bf(vy - hf);
          YH[(w*16 + quad*4 + rg)*72 + ct*16 + lm] = hh;   // wave-local rows, no barrier
          YL[(w*16 + quad*4 + rg)*72 + ct*16 + lm] = ll;
        }
      }
    }
    // readback y A-frags (wave-local)
    const u16* yh_ = YH + (w*16+lm)*72;
    const u16* yl_ = YL + (w*16+lm)*72;
    bf16x8 Yh0 = *(const bf16x8*)(yh_ + quad*8);
    bf16x8 Yh1 = *(const bf16x8*)(yh_ + 32 + quad*8);
    bf16x8 Yl0 = *(const bf16x8*)(yl_ + quad*8);
    bf16x8 Yl1 = *(const bf16x8*)(yl_ + 32 + quad*8);

    float sr[4];
    #pragma unroll
    for (int r=0;r<4;++r) sr[r] = STS[r0 + quad*4 + r];

    // ---- two column-halves: score 16x128, select, emit (kv[32] per lane) ----
    for (int ch=0; ch<2; ++ch){
      int j0 = ch*128;
      u32 kv[32];
      #pragma unroll
      for (int ct=0; ct<8; ++ct){
        const u16* bh = XH + (j0 + ct*16+lm)*72;
        const u16* bl = XL + (j0 + ct*16+lm)*72;
        bf16x8 Bh0 = *(const bf16x8*)(bh + quad*8);
        bf16x8 Bh1 = *(const bf16x8*)(bh + 32 + quad*8);
        bf16x8 Bl0 = *(const bf16x8*)(bl + quad*8);
        bf16x8 Bl1 = *(const bf16x8*)(bl + 32 + quad*8);
        f32x4 a1 = {0.f,0.f,0.f,0.f}, a2 = {0.f,0.f,0.f,0.f};
        a1 = __builtin_amdgcn_mfma_f32_16x16x32_bf16(Yh0, Bh0, a1, 0,0,0);
        a2 = __builtin_amdgcn_mfma_f32_16x16x32_bf16(Yh1, Bh1, a2, 0,0,0);
        a1 = __builtin_amdgcn_mfma_f32_16x16x32_bf16(Yl0, Bh0, a1, 0,0,0);
        a2 = __builtin_amdgcn_mfma_f32_16x16x32_bf16(Yl1, Bh1, a2, 0,0,0);
        a1 = __builtin_amdgcn_mfma_f32_16x16x32_bf16(Yh0, Bl0, a1, 0,0,0);
        a2 = __builtin_amdgcn_mfma_f32_16x16x32_bf16(Yh1, Bl1, a2, 0,0,0);
        float tc = STT[j0 + ct*16 + lm];
        #pragma unroll
        for (int r=0;r<4;++r)
          kv[ct*4 + r] = sortKey(a1[r] + a2[r] + sr[r] + tc);
      }

      // 16-bit-prefix threshold (top-128 of 2048), early-exit in [TOPK, CAP]
      u32 T = 0;
      for (int bit=15; bit>=0; --bit){
        u32 th2 = (T | (1u<<bit)) << 16;
        int c = 0;
        #pragma unroll
        for (int i=0;i<32;++i)
          c += (int)__popcll(__ballot(kv[i] >= th2));
        if (c >= TOPK){
          T |= (1u<<bit);
          if (c <= CAP) break;
        }
      }
      u32 thr = T << 16;
      u32 up  = (T < 0xffffu) ? ((T+1u) << 16) : 0xffffffffu;

      // two-class emission: above-bucket first (count < 128 guaranteed), then T-bucket
      u32 m1 = 0, m2 = 0;
      #pragma unroll
      for (int i=0;i<32;++i){
        bool ge = kv[i] >= thr;
        bool c1 = ge && (kv[i] >= up);
        m1 |= (c1 ? 1u : 0u) << i;
        m2 |= ((ge && !c1) ? 1u : 0u) << i;
      }
      int n1 = __popc(m1), n2 = __popc(m2);
      int p1 = n1, p2 = n2;
      #pragma unroll
      for (int off=1; off<64; off<<=1){
        int a = __shfl_up(p1, off); if (lane >= off) p1 += a;
        int c = __shfl_up(p2, off); if (lane >= off) p2 += c;
      }
      int tot1 = __shfl(p1, 63), tot2 = __shfl(p2, 63);
      int pos1 = p1 - n1;
      int pos2 = tot1 + (p2 - n2);
      int total = tot1 + tot2;
      int wt = u*2 + ch;
      size_t base = ((size_t)b*NWT + wt)*CAP;
      if (lane == 0) cand_n[b*NWT + wt] = (total < CAP) ? total : CAP;
      while (m1){
        int i = __ffs(m1) - 1; m1 &= m1 - 1;
        if (pos1 < CAP){
          int r = i & 3, ct = i >> 2;
          int flat = (r0 + quad*4 + r)*L_SEQ + (j0 + ct*16 + lm);
          cand[base + pos1] = ((u64)kv[i] << 32) | (u32)flat;
        }
        ++pos1;
      }
      while (m2){
        int i = __ffs(m2) - 1; m2 &= m2 - 1;
        if (pos2 < CAP){
          int r = i & 3, ct = i >> 2;
          int flat = (r0 + quad*4 + r)*L_SEQ + (j0 + ct*16 + lm);
          cand[base + pos2] = ((u64)kv[i] << 32) | (u32)flat;
        }
        ++pos2;
      }
    }
  }
}

// ---------- FALLBACK K1: split x; st; y via MFMA ----------
__global__ __launch_bounds__(256) void k_pre(
    const float* __restrict__ x, const u16* __restrict__ MtH, const u16* __restrict__ MtL,
    const float* __restrict__ uvc,
    u16* __restrict__ xh, u16* __restrict__ xl,
    u16* __restrict__ yh, u16* __restrict__ yl,
    float* __restrict__ st)
{
  __shared__ __align__(16) u16 sh[64][72];
  __shared__ __align__(16) u16 sl[64][72];
  __shared__ float sUV[132];
  int tid = threadIdx.x;
  int g0 = blockIdx.x * 64;
  int b  = g0 >> 8, l0 = g0 & 255;
  int r = tid >> 2, q = tid & 3;

  if (tid < 129) sUV[tid] = uvc[tid];

  float v[16];
  {
    const float* xr = x + (size_t)(g0 + r)*D_IN + q*16;
    #pragma unroll
    for (int i=0;i<4;++i) *(float4*)&v[i*4] = *(const float4*)(xr + i*4);
  }
  {
    u32 hpA[4],lpA[4],hpB[4],lpB[4];
    cvt8(&v[0], hpA, lpA); cvt8(&v[8], hpB, lpB);
    size_t xo = (size_t)(g0 + r)*D_IN + q*16;
    *(uint4*)(xh + xo)     = make_uint4(hpA[0],hpA[1],hpA[2],hpA[3]);
    *(uint4*)(xh + xo + 8) = make_uint4(hpB[0],hpB[1],hpB[2],hpB[3]);
    *(uint4*)(xl + xo)     = make_uint4(lpA[0],lpA[1],lpA[2],lpA[3]);
    *(uint4*)(xl + xo + 8) = make_uint4(lpB[0],lpB[1],lpB[2],lpB[3]);
    *(uint4*)&sh[r][q*16]   = make_uint4(hpA[0],hpA[1],hpA[2],hpA[3]);
    *(uint4*)&sh[r][q*16+8] = make_uint4(hpB[0],hpB[1],hpB[2],hpB[3]);
    *(uint4*)&sl[r][q*16]   = make_uint4(lpA[0],lpA[1],lpA[2],lpA[3]);
    *(uint4*)&sl[r][q*16+8] = make_uint4(lpB[0],lpB[1],lpB[2],lpB[3]);
  }
  __syncthreads();

  {
    float su=0.f, tv=0.f, pa=0.f;
    #pragma unroll
    for (int d=0; d<16; ++d){
      float xa = v[d];
      su = fmaf(xa, sUV[q*16+d], su);
      tv = fmaf(xa, sUV[64+q*16+d], tv);
      pa += fabsf(xa);
    }
    su += __shfl_xor(su,1); su += __shfl_xor(su,2);
    tv += __shfl_xor(tv,1); tv += __shfl_xor(tv,2);
    pa += __shfl_xor(pa,1); pa += __shfl_xor(pa,2);
    if (q == 0){
      bool pad = (pa != 0.f);
      st[(size_t)b*L_SEQ + l0 + r]          = pad ? (su + sUV[128]) : -1e38f;
      st[(size_t)(B_TOT+b)*L_SEQ + l0 + r]  = pad ? tv : -1e38f;
    }
  }

  int w = tid >> 6, lane = tid & 63, lm = lane & 15, quad = lane >> 4;
  bf16x8 Ah0 = *(const bf16x8*)&sh[w*16+lm][quad*8];
  bf16x8 Ah1 = *(const bf16x8*)&sh[w*16+lm][32 + quad*8];
  bf16x8 Al0 = *(const bf16x8*)&sl[w*16+lm][quad*8];
  bf16x8 Al1 = *(const bf16x8*)&sl[w*16+lm][32 + quad*8];
  #pragma unroll
  for (int ct=0; ct<4; ++ct){
    const u16* mth = MtH + (ct*16+lm)*64 + quad*8;
    const u16* mtl = MtL + (ct*16+lm)*64 + quad*8;
    bf16x8 Bh0 = *(const bf16x8*)(mth);
    bf16x8 Bh1 = *(const bf16x8*)(mth + 32);
    bf16x8 Bl0 = *(const bf16x8*)(mtl);
    bf16x8 Bl1 = *(const bf16x8*)(mtl + 32);
    f32x4 a1 = {0.f,0.f,0.f,0.f}, a2 = {0.f,0.f,0.f,0.f};
    a1 = __builtin_amdgcn_mfma_f32_16x16x32_bf16(Ah0, Bh0, a1, 0,0,0);
    a2 = __builtin_amdgcn_mfma_f32_16x16x32_bf16(Ah1, Bh1, a2, 0,0,0);
    a1 = __builtin_amdgcn_mfma_f32_16x16x32_bf16(Al0, Bh0, a1, 0,0,0);
    a2 = __builtin_amdgcn_mfma_f32_16x16x32_bf16(Al1, Bh1, a2, 0,0,0);
    a1 = __builtin_amdgcn_mfma_f32_16x16x32_bf16(Ah0, Bl0, a1, 0,0,0);
    a2 = __builtin_amdgcn_mfma_f32_16x16x32_bf16(Ah1, Bl1, a2, 0,0,0);
    #pragma unroll
    for (int rg=0; rg<4; ++rg){
      float vy = a1[rg] + a2[rg];
      u16 hh = f2bf(vy); float hf = __uint_as_float(((u32)hh)<<16);
      u16 ll = f2bf(vy - hf);
      sh[w*16 + quad*4 + rg][ct*16 + lm] = hh;
      sl[w*16 + quad*4 + rg][ct*16 + lm] = ll;
    }
  }
  {
    size_t yo = (size_t)(g0 + r)*D_IN + q*16;
    *(uint4*)(yh + yo)     = *(uint4*)&sh[r][q*16];
    *(uint4*)(yh + yo + 8) = *(uint4*)&sh[r][q*16+8];
    *(uint4*)(yl + yo)     = *(uint4*)&sl[r][q*16];
    *(uint4*)(yl + yo + 8) = *(uint4*)&sl[r][q*16+8];
  }
}

// ---------- FALLBACK K2: k_score ----------
__global__ __launch_bounds__(256) void k_score(
    const u16* __restrict__ xh, const u16* __restrict__ xl,
    const u16* __restrict__ yh, const u16* __restrict__ yl,
    const float* __restrict__ st,
    u64* __restrict__ cand, int* __restrict__ cand_n)
{
  int tid = threadIdx.x;
  int lin = blockIdx.x;
  int b    = ((lin >> 6) << 3) | (lin & 7);
  int tile = (lin >> 3) & 7;
  int cb = tile & 1, rb = tile >> 1;
  int r0 = rb*64, j0 = cb*128;
  int w = tid >> 6, lane = tid & 63, lm = lane & 15, quad = lane >> 4;

  size_t rowA = ((size_t)b*L_SEQ + r0 + w*16 + lm)*D_IN;
  bf16x8 A_h0 = *(const bf16x8*)(yh + rowA + quad*8);
  bf16x8 A_h1 = *(const bf16x8*)(yh + rowA + 32 + quad*8);
  bf16x8 A_l0 = *(const bf16x8*)(yl + rowA + quad*8);
  bf16x8 A_l1 = *(const bf16x8*)(yl + rowA + 32 + quad*8);

  float4 s4 = *(const float4*)(st + (size_t)b*L_SEQ + r0 + w*16 + quad*4);
  float sr[4] = {s4.x, s4.y, s4.z, s4.w};
  float tc[8];
  #pragma unroll
  for (int ct=0;ct<8;++ct)
    tc[ct] = st[(size_t)(B_TOT + b)*L_SEQ + j0 + ct*16 + lm];

  u32 kv[32];
  #pragma unroll
  for (int ct=0; ct<8; ++ct){
    size_t rowB = ((size_t)b*L_SEQ + j0 + ct*16 + lm)*D_IN;
    bf16x8 B_h0 = *(const bf16x8*)(xh + rowB + quad*8);
    bf16x8 B_h1 = *(const bf16x8*)(xh + rowB + 32 + quad*8);
    bf16x8 B_l0 = *(const bf16x8*)(xl + rowB + quad*8);
    bf16x8 B_l1 = *(const bf16x8*)(xl + rowB + 32 + quad*8);
    f32x4 a1 = {0.f,0.f,0.f,0.f}, a2 = {0.f,0.f,0.f,0.f};
    a1 = __builtin_amdgcn_mfma_f32_16x16x32_bf16(A_h0, B_h0, a1, 0,0,0);
    a2 = __builtin_amdgcn_mfma_f32_16x16x32_bf16(A_h1, B_h1, a2, 0,0,0);
    a1 = __builtin_amdgcn_mfma_f32_16x16x32_bf16(A_l0, B_h0, a1, 0,0,0);
    a2 = __builtin_amdgcn_mfma_f32_16x16x32_bf16(A_l1, B_h1, a2, 0,0,0);
    a1 = __builtin_amdgcn_mfma_f32_16x16x32_bf16(A_h0, B_l0, a1, 0,0,0);
    a2 = __builtin_amdgcn_mfma_f32_16x16x32_bf16(A_h1, B_l1, a2, 0,0,0);
    #pragma unroll
    for (int r=0;r<4;++r)
      kv[ct*4 + r] = sortKey(a1[r] + a2[r] + sr[r] + tc[ct]);
  }

  u32 T = 0;
  for (int bit=15; bit>=0; --bit){
    u32 th2 = (T | (1u<<bit)) << 16;
    int c = 0;
    #pragma unroll
    for (int i=0;i<32;++i)
      c += (int)__popcll(__ballot(kv[i] >= th2));
    if (c >= TOPK){
      T |= (1u<<bit);
      if (c <= CAP) break;
    }
  }
  u32 thr = T << 16;

  u32 hm = 0;
  #pragma unroll
  for (int i=0;i<32;++i) hm |= (kv[i] >= thr ? 1u : 0u) << i;
  int myc = __popc(hm);
  int pre = myc;
  #pragma unroll
  for (int off=1; off<64; off<<=1){
    int n = __shfl_up(pre, off);
    if (lane >= off) pre += n;
  }
  int total = __shfl(pre, 63);
  int pos = pre - myc;
  int wt = tile*4 + w;
  size_t base = ((size_t)b*NWT + wt)*CAP;
  if (lane == 0) cand_n[b*NWT + wt] = (total < CAP) ? total : CAP;
  while (hm){
    int i = __ffs(hm) - 1; hm &= hm - 1;
    if (pos < CAP){
      int r = i & 3, ct = i >> 2;
      int flat = (r0 + w*16 + quad*4 + r)*L_SEQ + (j0 + ct*16 + lm);
      cand[base + pos] = ((u64)kv[i] << 32) | (u32)flat;
    }
    ++pos;
  }
}

// ---------- K3: two-stage ballot merge -> exact top-128 + softmax ----------
__global__ __launch_bounds__(256) void k_merge(
    const u64* __restrict__ cand, const int* __restrict__ cand_n,
    int* __restrict__ selidx, float* __restrict__ selw)
{
  const int SL   = NWT/4;           // 8 slots per wave
  const int NSW  = SL*CAP/64;       // 20 keys per lane
  const int WCAP = 192;
  __shared__ u64 wbuf[4][WCAP];
  __shared__ int wcnt[4];
  __shared__ int scnt[NWT];
  __shared__ int cm, eqc;
  __shared__ int eqi[256];
  __shared__ float sv[TOPK]; __shared__ int si[TOPK];
  __shared__ float fred[8];
  int b = blockIdx.x, tid = threadIdx.x;
  int w = tid >> 6, lane = tid & 63;
  if (tid < NWT) scnt[tid] = cand_n[b*NWT + tid];
  if (tid == 0){ cm = 0; eqc = 0; }
  __syncthreads();

  u32 key[NSW]; int idx[NSW];
  size_t bb = (size_t)b*NWT*CAP + (size_t)(w*SL)*CAP;
  #pragma unroll
  for (int s=0;s<NSW;++s){
    int e = lane + 64*s;
    int slot = e / CAP, p = e - slot*CAP;
    bool ok = p < scnt[w*SL + slot];
    u64 v = ok ? cand[bb + e] : 0ull;
    key[s] = (u32)(v >> 32);
    idx[s] = ok ? (int)(u32)v : 0x7fffffff;
  }

  u32 T = 0;
  for (int bit=31; bit>=0; --bit){
    u32 c2 = T | (1u<<bit);
    int c = 0;
    #pragma unroll
    for (int s=0;s<NSW;++s) c += (int)__popcll(__ballot(key[s] >= c2));
    if (c >= TOPK){
      T = c2;
      if (c <= WCAP) break;
    }
  }
  {
    int myc = 0;
    #pragma unroll
    for (int s=0;s<NSW;++s) myc += (key[s] >= T) ? 1 : 0;
    int pre = myc;
    #pragma unroll
    for (int off=1; off<64; off<<=1){
      int n = __shfl_up(pre, off);
      if (lane >= off) pre += n;
    }
    int total = __shfl(pre, 63);
    int pos = pre - myc;
    if (lane == 0) wcnt[w] = (total < WCAP) ? total : WCAP;
    #pragma unroll
    for (int s=0;s<NSW;++s){
      if (key[s] >= T){
        if (pos < WCAP) wbuf[w][pos] = ((u64)key[s] << 32) | (u32)idx[s];
        ++pos;
      }
    }
  }
  __syncthreads();

  if (w == 0){
    const int NS2 = 4*WCAP/64;   // 12
    u32 k2[NS2]; int i2[NS2];
    #pragma unroll
    for (int s=0;s<NS2;++s){
      int e = lane + 64*s;
      int slot = e / WCAP, p = e - slot*WCAP;
      bool ok = p < wcnt[slot];
      u64 v = ok ? wbuf[slot][p] : 0ull;
      k2[s] = (u32)(v >> 32);
      i2[s] = ok ? (int)(u32)v : 0x7fffffff;
    }
    u32 T2 = 0;
    for (int bit=31; bit>=0; --bit){
      u32 c2 = T2 | (1u<<bit);
      int c = 0;
      #pragma unroll
      for (int s=0;s<NS2;++s) c += (int)__popcll(__ballot(k2[s] >= c2));
      if (c >= TOPK) T2 = c2;
    }
    int m = 0;
    #pragma unroll
    for (int s=0;s<NS2;++s) m += (int)__popcll(__ballot(k2[s] > T2));
    #pragma unroll
    for (int s=0;s<NS2;++s){
      if (k2[s] > T2){
        int p = atomicAdd(&cm, 1);
        sv[p] = unKey(k2[s]) * 0.0625f; si[p] = i2[s];
      } else if (k2[s] == T2 && i2[s] != 0x7fffffff){
        int q = atomicAdd(&eqc, 1);
        if (q < 256) eqi[q] = i2[s];
      }
    }
    if (lane == 0){
      int need = TOPK - m;
      int n = eqc < 256 ? eqc : 256;
      float tv = unKey(T2) * 0.0625f;
      for (int s2=0; s2<need; ++s2){
        int bi = s2;
        for (int j=s2+1;j<n;++j) if (eqi[j] < eqi[bi]) bi = j;
        int t2 = eqi[s2]; eqi[s2] = eqi[bi]; eqi[bi] = t2;
        sv[m+s2] = tv; si[m+s2] = eqi[s2];
      }
    }
  }
  __syncthreads();

  float v = (tid < TOPK) ? sv[tid] : -3.4e38f;
  float mx = v;
  #pragma unroll
  for (int off=1; off<64; off<<=1) mx = fmaxf(mx, __shfl_xor(mx, off));
  if ((tid&63)==0) fred[tid>>6] = mx;
  __syncthreads();
  mx = fmaxf(fred[0], fred[1]);
  float e = (tid < TOPK) ? expf(v - mx) : 0.f;
  float s = e;
  #pragma unroll
  for (int off=1; off<64; off<<=1) s += __shfl_xor(s, off);
  if ((tid&63)==0) fred[4 + (tid>>6)] = s;
  __syncthreads();
  s = fred[4] + fred[5];
  if (tid < TOPK){
    selw[(size_t)b*TOPK + tid]   = e / s;
    selidx[(size_t)b*TOPK + tid] = si[tid];
  }
}

// ---------- K4: gather + split-bf16 MFMA MLP1 + pooling + rho (r9 256-thread version) ----------
__global__ __launch_bounds__(256) void k_mlp(
    const float* __restrict__ x, const int* __restrict__ selidx, const float* __restrict__ selw,
    const u16* __restrict__ xiH, const u16* __restrict__ xiL,
    const u16* __restrict__ phiH, const u16* __restrict__ phiL,
    const float* __restrict__ phi_b1, const float* __restrict__ phi_w2, const float* __restrict__ phi_b2,
    const float* __restrict__ xi_b1,  const float* __restrict__ xi_w2,  const float* __restrict__ xi_b2,
    const float* __restrict__ rho_w1, const float* __restrict__ rho_b1,
    const float* __restrict__ rho_w2, const float* __restrict__ rho_b2,
    float* __restrict__ out)
{
  __shared__ __align__(16) u16 AFh[8][4][64][8];
  __shared__ __align__(16) u16 AFl[8][4][64][8];
  __shared__ int   sidx[TOPK];
  __shared__ float swp[TOPK], swd[TOPK];
  __shared__ float gpL[256], gsL[256];
  __shared__ float pooled[256], t1[256];
  __shared__ float wsums[2];
  int b = blockIdx.x, tid = threadIdx.x;

  if (tid < TOPK){
    int fl = selidx[(size_t)b*TOPK + tid];
    sidx[tid] = fl;
    float wv = selw[(size_t)b*TOPK + tid];
    bool dg = ((fl>>8) == (fl&255));
    swp[tid] = dg ? 0.f : wv;
    swd[tid] = dg ? wv  : 0.f;
  }
  __syncthreads();
  if (tid == 0){
    float a=0.f, c2=0.f;
    for (int k=0;k<TOPK;++k){ a+=swp[k]; c2+=swd[k]; }
    wsums[0]=a; wsums[1]=c2;
  }
  {
    int m = tid >> 1, hf = tid & 1;
    int fl = sidx[m];
    int rc = hf ? (fl & 255) : (fl >> 8);
    const float* src = x + ((size_t)b*L_SEQ + rc)*D_IN;
    int kt = m >> 4, l16 = m & 15;
    #pragma unroll
    for (int g=0; g<8; ++g){
      int d0 = hf*64 + g*8;
      int c = d0 >> 5, q = (d0 >> 3) & 3;
      float v[8];
      *(float4*)&v[0] = *(const float4*)(src + (d0 & 63));
      *(float4*)&v[4] = *(const float4*)(src + (d0 & 63) + 4);
      u32 hp[4], lp[4];
      cvt8(v, hp, lp);
      *(uint4*)&AFh[kt][c][l16 + 16*q][0] = make_uint4(hp[0],hp[1],hp[2],hp[3]);
      *(uint4*)&AFl[kt][c][l16 + 16*q][0] = make_uint4(lp[0],lp[1],lp[2],lp[3]);
    }
  }
  __syncthreads();

  int w = tid >> 6, lane = tid & 63;
  int lm = lane & 15, quad = lane >> 4;

  #pragma unroll
  for (int hi4=0; hi4<4; ++hi4){
    int ht = w + 4*hi4;
    int h  = ht*16 + lm;
    bf16x8 BXh[4], BXl[4], BPh[2], BPl[2];
    #pragma unroll
    for (int c=0;c<4;++c){
      BXh[c] = *(const bf16x8*)(xiH + h*128 + c*32 + quad*8);
      BXl[c] = *(const bf16x8*)(xiL + h*128 + c*32 + quad*8);
    }
    #pragma unroll
    for (int c=0;c<2;++c){
      BPh[c] = *(const bf16x8*)(phiH + h*64 + c*32 + quad*8);
      BPl[c] = *(const bf16x8*)(phiL + h*64 + c*32 + quad*8);
    }
    float bxi = xi_b1[h], bph = phi_b1[h];
    float gp = 0.f, gs = 0.f;
    for (int kt=0; kt<8; ++kt){
      bf16x8 Ah_[4], Al_[4];
      #pragma unroll
      for (int c=0;c<4;++c){
        Ah_[c] = *(const bf16x8*)&AFh[kt][c][lane][0];
        Al_[c] = *(const bf16x8*)&AFl[kt][c][lane][0];
      }
      f32x4 cx = {0.f,0.f,0.f,0.f}, cp = {0.f,0.f,0.f,0.f};
      #pragma unroll
      for (int c=0;c<4;++c){
        cx = __builtin_amdgcn_mfma_f32_16x16x32_bf16(Ah_[c], BXh[c], cx, 0,0,0);
        cx = __builtin_amdgcn_mfma_f32_16x16x32_bf16(Al_[c], BXh[c], cx, 0,0,0);
        cx = __builtin_amdgcn_mfma_f32_16x16x32_bf16(Ah_[c], BXl[c], cx, 0,0,0);
      }
      #pragma unroll
      for (int c=0;c<2;++c){
        cp = __builtin_amdgcn_mfma_f32_16x16x32_bf16(Ah_[c], BPh[c], cp, 0,0,0);
        cp = __builtin_amdgcn_mfma_f32_16x16x32_bf16(Al_[c], BPh[c], cp, 0,0,0);
        cp = __builtin_amdgcn_mfma_f32_16x16x32_bf16(Ah_[c], BPl[c], cp, 0,0,0);
      }
      #pragma unroll
      for (int r=0;r<4;++r){
        int kk = kt*16 + quad*4 + r;
        gp = fmaf(swp[kk], fmaxf(cx[r] + bxi, 0.f), gp);
        gs = fmaf(swd[kk], fmaxf(cp[r] + bph, 0.f), gs);
      }
    }
    gp += __shfl_xor(gp, 16); gp += __shfl_xor(gp, 32);
    gs += __shfl_xor(gs, 16); gs += __shfl_xor(gs, 32);
    if (quad == 0){ gpL[h] = gp; gsL[h] = gs; }
  }
  __syncthreads();

  int h = tid;
  {
    float wsp = wsums[0], wss = wsums[1];
    float po = wsp*xi_b2[h] + wss*phi_b2[h];
    for (int d=0; d<256; ++d){
      po = fmaf(gpL[d], xi_w2[d*HIDN + h], po);
      po = fmaf(gsL[d], phi_w2[d*HIDN + h], po);
    }
    pooled[h] = po;
  }
  __syncthreads();
  {
    float a = rho_b1[h];
    for (int d=0; d<256; ++d) a = fmaf(pooled[d], rho_w1[d*HIDN + h], a);
    t1[h] = fmaxf(a, 0.f);
  }
  __syncthreads();
  if (h < 128){
    float o = rho_b2[h];
    for (int d=0; d<256; ++d) o = fmaf(t1[d], rho_w2[d*128 + h], o);
    out[(size_t)b*128 + h] = o;
  }
}

// ---------- host ----------
extern "C" void kernel_launch(void* const* d_in, const int* in_sizes, int n_in,
                              void* d_out, int out_size, void* d_ws, size_t ws_size,
                              hipStream_t stream)
{
  (void)in_sizes; (void)n_in; (void)out_size; (void)ws_size;
  const float* x      = (const float*)d_in[0];
  const float* Wq     = (const float*)d_in[1];
  const float* bq     = (const float*)d_in[2];
  const float* Wk     = (const float*)d_in[3];
  const float* bk     = (const float*)d_in[4];
  const float* phi_w1 = (const float*)d_in[5];
  const float* phi_b1 = (const float*)d_in[6];
  const float* phi_w2 = (const float*)d_in[7];
  const float* phi_b2 = (const float*)d_in[8];
  const float* xi_w1  = (const float*)d_in[9];
  const float* xi_b1  = (const float*)d_in[10];
  const float* xi_w2  = (const float*)d_in[11];
  const float* xi_b2  = (const float*)d_in[12];
  const float* rho_w1 = (const float*)d_in[13];
  const float* rho_b1 = (const float*)d_in[14];
  const float* rho_w2 = (const float*)d_in[15];
  const float* rho_b2 = (const float*)d_in[16];
  float* out = (float*)d_out;

  const size_t NX = (size_t)B_TOT*L_SEQ*D_IN;      // 8,388,608
  float* uvc    = (float*)d_ws;                    // 256
  float* st     = uvc + 256;                       // 2*512*256
  float* selw   = st + (size_t)2*B_TOT*L_SEQ;      // 512*128
  int*   selidx = (int*)(selw + (size_t)B_TOT*TOPK);
  int*   cand_n = selidx + (size_t)B_TOT*TOPK;     // 512*32
  u64*   cand   = (u64*)(cand_n + (size_t)B_TOT*NWT);
  u16*   MtH    = (u16*)(cand + (size_t)B_TOT*NWT*CAP);
  u16*   MtL    = MtH + 64*64;
  u16*   xiH    = MtL + 64*64;
  u16*   xiL    = xiH + 256*128;
  u16*   phiH   = xiL + 256*128;
  u16*   phiL   = phiH + 256*64;
  u16*   xh     = phiL + 256*64;
  u16*   xl     = xh + NX;
  u16*   yh     = xl + NX;
  u16*   yl     = yh + NX;

  // deterministic per-device check (same result every call -> graph-safe)
  hipError_t aerr = hipFuncSetAttribute((const void*)k_fused,
                      hipFuncAttributeMaxDynamicSharedMemorySize, FLDS);

  k_wprep<<<dim3(256),  dim3(256), 0, stream>>>(Wq, bq, Wk, bk, xi_w1, phi_w1,
                                                MtH, MtL, uvc, xiH, xiL, phiH, phiL);
  if (aerr == hipSuccess){
    k_fused<<<dim3(B_TOT), dim3(512), FLDS, stream>>>(x, MtH, MtL, uvc, cand, cand_n);
  } else {
    k_pre  <<<dim3(2048), dim3(256), 0, stream>>>(x, MtH, MtL, uvc, xh, xl, yh, yl, st);
    k_score<<<dim3(4096), dim3(256), 0, stream>>>(xh, xl, yh, yl, st, cand, cand_n);
  }
  k_merge<<<dim3(B_TOT), dim3(256), 0, stream>>>(cand, cand_n, selidx, selw);
  k_mlp  <<<dim3(B_TOT), dim3(256), 0, stream>>>(x, selidx, selw,
            xiH, xiL, phiH, phiL,
            phi_b1, phi_w2, phi_b2,
            xi_b1, xi_w2, xi_b2,
            rho_w1, rho_b1, rho_w2, rho_b2, out);
}